// Round 14
// baseline (116.937 us; speedup 1.0000x reference)
//
#include <hip/hip_runtime.h>

#define LN_EPS 1e-3f

typedef __attribute__((ext_vector_type(8))) short bf16x8;
typedef __attribute__((ext_vector_type(4))) float f32x4;

static __device__ __forceinline__ float sgnf(float x) {
    return (x > 0.f) ? 1.f : ((x < 0.f) ? -1.f : 0.f);
}
// silu via single-instruction v_rcp_f32: denominator > 0 so sign(silu(x)) == sign(x).
static __device__ __forceinline__ float siluf(float x) {
    return x * __builtin_amdgcn_rcpf(1.f + __expf(-x));
}

// round-to-nearest-even fp32 -> bf16 bits
static __device__ __forceinline__ unsigned short f2bf(float f) {
    unsigned int u = __float_as_uint(f);
    return (unsigned short)((u + 0x7fffu + ((u >> 16) & 1u)) >> 16);
}
static __device__ __forceinline__ float bf2f(unsigned short s) {
    return __uint_as_float(((unsigned int)s) << 16);
}
// exact 3-way bf16 split: v = hi + mid + lo (+ O(2^-27) rel)
static __device__ __forceinline__ void split3(float v, unsigned short& hi,
                                              unsigned short& mid, unsigned short& lo) {
    hi = f2bf(v);
    const float r1 = v - bf2f(hi);       // exact (Sterbenz)
    mid = f2bf(r1);
    const float r2 = r1 - bf2f(mid);     // exact
    lo = f2bf(r2);
}

// ================= FAST PATH (MFMA) — requires ws_size >= 794624 =================
// ws layout (bytes):
//   [0, 786432)          Bpack: bf16 H^T fragments, 3-way split, part-major (coalesced)
//     bf16x8 index = ((c*2+ks)*64 + ntg)*192 + part*64 + lane
//   [786432, 794624)     sp[2][1024] fp32   (float offset 196608)
#define SPOFF 196608

// ---------------- fast prep 1: sp ----------------
__global__ __launch_bounds__(256) void hd_prep_sp(
    const float* __restrict__ h, const float* __restrict__ symbols,
    const float* __restrict__ gamma, const float* __restrict__ beta,
    float* __restrict__ ws)
{
    __shared__ float h_pad[2][1088];
    __shared__ float x_s[2][64];
    __shared__ float red[4][2];
    const int t = threadIdx.x;

    for (int idx = t; idx < 2 * 1088; idx += 256) {
        const int c = idx / 1088, j = idx - c * 1088;
        float v = 0.f;
        if (j >= 63 && j <= 1023) v = h[c * 961 + (j - 63)];
        h_pad[c][j] = v;
    }
    if (t < 128) x_s[t >> 6][t & 63] = symbols[t];
    __syncthreads();

    const int c = t >> 7, tt = t & 127;
    const int lane = t & 63, wid = t >> 6;
    const int jbase = 1023 - tt;

    float acc[8];
    #pragma unroll
    for (int k = 0; k < 8; ++k) acc[k] = 0.f;

    #pragma unroll 8
    for (int i = 0; i < 64; ++i) {
        const float xv = x_s[c][i];
        #pragma unroll
        for (int k = 0; k < 8; ++k)
            acc[k] = fmaf(xv, h_pad[c][jbase + i - 128 * k], acc[k]);
    }

    float ps = 0.f, pq = 0.f;
    #pragma unroll
    for (int k = 0; k < 8; ++k) { ps += acc[k]; pq += acc[k] * acc[k]; }
    #pragma unroll
    for (int off = 32; off; off >>= 1) {
        ps += __shfl_xor(ps, off);
        pq += __shfl_xor(pq, off);
    }
    if (lane == 0) { red[wid][0] = ps; red[wid][1] = pq; }
    __syncthreads();

    const float sum = red[2 * c][0] + red[2 * c + 1][0];
    const float sq  = red[2 * c][1] + red[2 * c + 1][1];
    const float mu  = sum * (1.f / 1024.f);
    float var = sq * (1.f / 1024.f) - mu * mu;
    var = fmaxf(var, 0.f);
    const float rs = rsqrtf(var + LN_EPS);

    #pragma unroll
    for (int k = 0; k < 8; ++k) {
        const int d = tt + 128 * k;
        const float ln = (acc[k] - mu) * rs * gamma[d] + beta[d];
        ws[SPOFF + c * 1024 + d] = siluf(ln);
    }
}

// ---------------- fast prep 2: Bpack (part-major layout) ----------------
__global__ __launch_bounds__(256) void hd_prep_bpack(
    const float* __restrict__ h, float* __restrict__ ws)
{
    unsigned short* Bp = (unsigned short*)ws;
    const int total = 2 * 2 * 64 * 64 * 8;   // 131072 positions, 3 parts each
    for (int e = blockIdx.x * 256 + threadIdx.x; e < total; e += gridDim.x * 256) {
        const int j   = e & 7;
        const int l   = (e >> 3) & 63;
        const int ntg = (e >> 9) & 63;
        const int ks  = (e >> 15) & 1;
        const int c   = (e >> 16) & 1;
        const int H = 1023 - (16 * ntg + (l & 15)) + 32 * ks + 8 * (l >> 4) + j;
        float v = 0.f;
        if (H >= 63 && H <= 1023) v = h[c * 961 + (H - 63)];
        unsigned short hi, mid, lo;
        split3(v, hi, mid, lo);
        const int T = (c * 2 + ks) * 64 + ntg;
        Bp[((T * 192 +   0 + l)) * 8 + j] = hi;
        Bp[((T * 192 +  64 + l)) * 8 + j] = mid;
        Bp[((T * 192 + 128 + l)) * 8 + j] = lo;
    }
}

// ---------------- fast main: 1024 thr (16 waves), wave w -> d in [64w, 64w+64) ----------------
// waves_per_eu(4,4): pin allocator's occupancy target at 4 waves/EU -> 128 VGPR budget,
// prevents the spill-to-reach-8-waves behavior seen at VGPR_Count=64 (R12: +68MB WRITE).
__global__ __launch_bounds__(1024) __attribute__((amdgpu_waves_per_eu(4, 4)))
void hd_main_mfma(
    const float* __restrict__ values,
    const float* __restrict__ gamma, const float* __restrict__ beta,
    const float* __restrict__ ws, float* __restrict__ out)
{
    __shared__ __align__(16) unsigned short a_lds[2][2][3][16][40];
    __shared__ float stats[16][4][2][4][2];  // [wave][g][c][r][sum,sq]
    __shared__ int   sred [16][4][2][4][2];  // [wave][g][c][r][a]
    __shared__ float statsF[64];             // [g][c][r][s]
    __shared__ int   sredF [64];             // [g][c][r][a]
    __shared__ float otile[16][4][72];       // per-WAVE store tile

    const int t = threadIdx.x;
    const int w = t >> 6, l = t & 63;
    const int g = l >> 4, q = l & 15;
    const int b0 = blockIdx.x * 16;

    // ---- cooperative A-fragment prep: 2048 x-values, thread t split3's values 2t, 2t+1
    {
        const float2 xv2 = *reinterpret_cast<const float2*>(
            values + (size_t)b0 * 128 + 2 * t);
        #pragma unroll
        for (int u = 0; u < 2; ++u) {
            const int v  = 2 * t + u;
            const int q_ = v >> 7, c_ = (v >> 6) & 1, k_ = v & 63;
            const int ks_ = k_ >> 5, gj = k_ & 31;
            unsigned short hb, mb, lb;
            split3(u == 0 ? xv2.x : xv2.y, hb, mb, lb);
            a_lds[c_][ks_][0][q_][gj] = hb;
            a_lds[c_][ks_][1][q_][gj] = mb;
            a_lds[c_][ks_][2][q_][gj] = lb;
        }
    }
    __syncthreads();

    // ---- A fragments from LDS (bit-identical to per-thread split)
    bf16x8 ahi[2][2], amd_[2][2], alo[2][2];
    #pragma unroll
    for (int c = 0; c < 2; ++c)
        #pragma unroll
        for (int ks = 0; ks < 2; ++ks) {
            ahi[c][ks]  = *reinterpret_cast<const bf16x8*>(&a_lds[c][ks][0][q][8 * g]);
            amd_[c][ks] = *reinterpret_cast<const bf16x8*>(&a_lds[c][ks][1][q][8 * g]);
            alo[c][ks]  = *reinterpret_cast<const bf16x8*>(&a_lds[c][ks][2][q][8 * g]);
        }

    // ---- MFMA (R10 body)
    const bf16x8* Bv = reinterpret_cast<const bf16x8*>(ws) + l;
    f32x4 acc[2][4];
    #pragma unroll
    for (int c = 0; c < 2; ++c)
        #pragma unroll
        for (int nt = 0; nt < 4; ++nt)
            acc[c][nt] = (f32x4){0.f, 0.f, 0.f, 0.f};

    __builtin_amdgcn_s_setprio(1);
    #pragma unroll
    for (int nt = 0; nt < 4; ++nt) {
        const int ntg = w * 4 + nt;
        #pragma unroll
        for (int c = 0; c < 2; ++c) {
            f32x4 ts = {0.f, 0.f, 0.f, 0.f};
            f32x4 tm = {0.f, 0.f, 0.f, 0.f};
            f32x4 th = {0.f, 0.f, 0.f, 0.f};
            #pragma unroll
            for (int ks = 0; ks < 2; ++ks) {
                const bf16x8* p = Bv + (size_t)((c * 2 + ks) * 64 + ntg) * 192;
                const bf16x8 bh = p[0], bm = p[64], bl = p[128];
                ts = __builtin_amdgcn_mfma_f32_16x16x32_bf16(amd_[c][ks], bl, ts, 0, 0, 0);
                ts = __builtin_amdgcn_mfma_f32_16x16x32_bf16(alo[c][ks], bm, ts, 0, 0, 0);
                ts = __builtin_amdgcn_mfma_f32_16x16x32_bf16(ahi[c][ks], bl, ts, 0, 0, 0);
                ts = __builtin_amdgcn_mfma_f32_16x16x32_bf16(amd_[c][ks], bm, ts, 0, 0, 0);
                ts = __builtin_amdgcn_mfma_f32_16x16x32_bf16(alo[c][ks], bh, ts, 0, 0, 0);
                tm = __builtin_amdgcn_mfma_f32_16x16x32_bf16(ahi[c][ks], bm, tm, 0, 0, 0);
                tm = __builtin_amdgcn_mfma_f32_16x16x32_bf16(amd_[c][ks], bh, tm, 0, 0, 0);
                th = __builtin_amdgcn_mfma_f32_16x16x32_bf16(ahi[c][ks], bh, th, 0, 0, 0);
            }
            #pragma unroll
            for (int r = 0; r < 4; ++r)
                acc[c][nt][r] = (ts[r] + tm[r]) + th[r];
        }
    }
    __builtin_amdgcn_s_setprio(0);

    // ---- LN stats: per (w,g,c,r) partial over q (shfl) -> LDS -> 2-stage block reduce
    {
        float s_[2][4], q_[2][4];
        #pragma unroll
        for (int c = 0; c < 2; ++c)
            #pragma unroll
            for (int r = 0; r < 4; ++r) { s_[c][r] = 0.f; q_[c][r] = 0.f; }
        #pragma unroll
        for (int c = 0; c < 2; ++c)
            #pragma unroll
            for (int nt = 0; nt < 4; ++nt)
                #pragma unroll
                for (int r = 0; r < 4; ++r) {
                    const float v = acc[c][nt][r];
                    s_[c][r] += v;
                    q_[c][r] += v * v;
                }
        #pragma unroll
        for (int off = 1; off < 16; off <<= 1)
            #pragma unroll
            for (int c = 0; c < 2; ++c)
                #pragma unroll
                for (int r = 0; r < 4; ++r) {
                    s_[c][r] += __shfl_xor(s_[c][r], off);
                    q_[c][r] += __shfl_xor(q_[c][r], off);
                }
        if (q == 0) {
            #pragma unroll
            for (int c = 0; c < 2; ++c)
                #pragma unroll
                for (int r = 0; r < 4; ++r) {
                    stats[w][g][c][r][0] = s_[c][r];
                    stats[w][g][c][r][1] = q_[c][r];
                }
        }
    }
    __syncthreads();
    if (t < 64) {   // t = ((g*2+c)*4+r)*2+s
        const int gg = t >> 4, cc = (t >> 3) & 1, rr = (t >> 1) & 3, ss = t & 1;
        float S = 0.f;
        #pragma unroll
        for (int w2 = 0; w2 < 16; ++w2) S += stats[w2][gg][cc][rr][ss];
        statsF[t] = S;
    }
    __syncthreads();

    float mu_[2][4], rs_[2][4];
    #pragma unroll
    for (int c = 0; c < 2; ++c)
        #pragma unroll
        for (int r = 0; r < 4; ++r) {
            const float S = statsF[((g * 2 + c) * 4 + r) * 2 + 0];
            const float Q = statsF[((g * 2 + c) * 4 + r) * 2 + 1];
            const float mu = S * (1.f / 1024.f);
            float var = Q * (1.f / 1024.f) - mu * mu;
            var = fmaxf(var, 0.f);
            mu_[c][r] = mu;
            rs_[c][r] = rsqrtf(var + LN_EPS);
        }

    // ---- vp = silu(LN(y)) in-place
    const int dbase = w * 64 + q;
    #pragma unroll
    for (int nt = 0; nt < 4; ++nt) {
        const int d = dbase + 16 * nt;
        const float gam = gamma[d];
        const float bet = beta[d];
        #pragma unroll
        for (int c = 0; c < 2; ++c)
            #pragma unroll
            for (int r = 0; r < 4; ++r)
                acc[c][nt][r] = siluf((acc[c][nt][r] - mu_[c][r]) * rs_[c][r] * gam + bet);
    }

    // ---- sp cached once (reused by sign-count and epilogue)
    float spv[2][4];
    #pragma unroll
    for (int nt = 0; nt < 4; ++nt) {
        const int d = dbase + 16 * nt;
        spv[0][nt] = ws[SPOFF + d];
        spv[1][nt] = ws[SPOFF + 1024 + d];
    }

    // ---- S sign-counts, PACKED: 16 counts (c,r,a) in 4 uints, 8-bit fields (max 64).
    unsigned int pk[4] = {0u, 0u, 0u, 0u};
    #pragma unroll
    for (int nt = 0; nt < 4; ++nt) {
        #pragma unroll
        for (int c = 0; c < 2; ++c)
            #pragma unroll
            for (int r = 0; r < 4; ++r) {
                const float v = acc[c][nt][r];
                const unsigned int iv = __float_as_uint(v);
                const unsigned int f0 = (iv ^ __float_as_uint(v + spv[0][nt])) >> 31;
                const unsigned int f1 = (iv ^ __float_as_uint(v + spv[1][nt])) >> 31;
                const int i0 = (c * 4 + r) * 2;       // a = 0
                const int i1 = i0 + 1;                // a = 1
                pk[i0 >> 2] += f0 << ((i0 & 3) * 8);
                pk[i1 >> 2] += f1 << ((i1 & 3) * 8);
            }
    }
    #pragma unroll
    for (int off = 1; off < 16; off <<= 1)
        #pragma unroll
        for (int v = 0; v < 4; ++v)
            pk[v] += __shfl_xor((int)pk[v], off);
    if (q == 0) {
        #pragma unroll
        for (int c = 0; c < 2; ++c)
            #pragma unroll
            for (int r = 0; r < 4; ++r)
                #pragma unroll
                for (int a = 0; a < 2; ++a) {
                    const int idx = (c * 4 + r) * 2 + a;
                    sred[w][g][c][r][a] =
                        (int)((pk[idx >> 2] >> ((idx & 3) * 8)) & 0xFFu);
                }
    }
    __syncthreads();
    if (t < 64) {   // t = ((g*2+c)*4+r)*2+a
        const int gg = t >> 4, cc = (t >> 3) & 1, rr = (t >> 1) & 3, aa = t & 1;
        int S = 0;
        #pragma unroll
        for (int w2 = 0; w2 < 16; ++w2) S += sred[w2][gg][cc][rr][aa];
        sredF[t] = S;
    }
    __syncthreads();

    // ---- softmax over c
    float p0_[4][2], p1_[4][2];
    #pragma unroll
    for (int r = 0; r < 4; ++r)
        #pragma unroll
        for (int a = 0; a < 2; ++a) {
            const int t0 = sredF[((g * 2 + 0) * 4 + r) * 2 + a];
            const int t1 = sredF[((g * 2 + 1) * 4 + r) * 2 + a];
            const float S0 = 1.f - 2.f * (float)t0 * (1.f / 1024.f);
            const float S1 = 1.f - 2.f * (float)t1 * (1.f / 1024.f);
            const float m  = fmaxf(S0, S1);
            const float e0 = __expf(S0 - m), e1 = __expf(S1 - m);
            const float inv = __builtin_amdgcn_rcpf(e0 + e1);
            p0_[r][a] = e0 * inv;
            p1_[r][a] = e1 * inv;
        }

    // ---- attn + silu + store. otile is wave-private; DS ops in-order per wave.
    const int g2 = l >> 4, qq = l & 15;
    #pragma unroll
    for (int a = 0; a < 2; ++a) {
        #pragma unroll
        for (int r = 0; r < 4; ++r) {
            #pragma unroll
            for (int nt = 0; nt < 4; ++nt) {
                const float attn = p0_[r][a] * acc[0][nt][r] + p1_[r][a] * acc[1][nt][r];
                otile[w][g][16 * nt + q] = siluf(attn * spv[a][nt]);
            }
            __builtin_amdgcn_wave_barrier();
            const float4 v4 = *reinterpret_cast<const float4*>(&otile[w][g2][4 * qq]);
            *reinterpret_cast<float4*>(
                out + ((size_t)(b0 + 4 * g2 + r) * 2 + a) * 1024 + 64 * w + 4 * qq) = v4;
            __builtin_amdgcn_wave_barrier();
        }
    }
}

// ================= FALLBACK PATH (scalar, R2-proven) =================
// ws floats: [0,2176) hrev ; [2176,4224) sp
__global__ __launch_bounds__(256) void hd_prep_scalar(
    const float* __restrict__ h, const float* __restrict__ symbols,
    const float* __restrict__ gamma, const float* __restrict__ beta,
    float* __restrict__ ws)
{
    __shared__ float h_pad[2][1088];
    __shared__ float x_s[2][64];
    __shared__ float red[4][2];
    const int t = threadIdx.x;

    for (int idx = t; idx < 2 * 1088; idx += 256) {
        const int c = idx / 1088, j = idx - c * 1088;
        float v = 0.f;
        if (j >= 63 && j <= 1023) v = h[c * 961 + (j - 63)];
        h_pad[c][j] = v;
        const int src = 1086 - j;
        float vr = 0.f;
        if (src >= 63 && src <= 1023) vr = h[c * 961 + (src - 63)];
        ws[c * 1088 + j] = vr;
    }
    if (t < 128) x_s[t >> 6][t & 63] = symbols[t];
    __syncthreads();

    const int c = t >> 7, tt = t & 127;
    const int lane = t & 63, wid = t >> 6;
    const int jbase = 1023 - tt;

    float acc[8];
    #pragma unroll
    for (int k = 0; k < 8; ++k) acc[k] = 0.f;

    #pragma unroll 8
    for (int i = 0; i < 64; ++i) {
        const float xv = x_s[c][i];
        #pragma unroll
        for (int k = 0; k < 8; ++k)
            acc[k] = fmaf(xv, h_pad[c][jbase + i - 128 * k], acc[k]);
    }

    float ps = 0.f, pq = 0.f;
    #pragma unroll
    for (int k = 0; k < 8; ++k) { ps += acc[k]; pq += acc[k] * acc[k]; }
    #pragma unroll
    for (int off = 32; off; off >>= 1) {
        ps += __shfl_xor(ps, off);
        pq += __shfl_xor(pq, off);
    }
    if (lane == 0) { red[wid][0] = ps; red[wid][1] = pq; }
    __syncthreads();

    const float sum = red[2 * c][0] + red[2 * c + 1][0];
    const float sq  = red[2 * c][1] + red[2 * c + 1][1];
    const float mu  = sum * (1.f / 1024.f);
    float var = sq * (1.f / 1024.f) - mu * mu;
    var = fmaxf(var, 0.f);
    const float rs = rsqrtf(var + LN_EPS);

    #pragma unroll
    for (int k = 0; k < 8; ++k) {
        const int d = tt + 128 * k;
        const float ln = (acc[k] - mu) * rs * gamma[d] + beta[d];
        ws[2176 + c * 1024 + d] = siluf(ln);
    }
}

__global__ __launch_bounds__(256, 4) void hd_main_scalar(
    const float* __restrict__ values,
    const float* __restrict__ gamma, const float* __restrict__ beta,
    const float* __restrict__ ws, float* __restrict__ out)
{
    __shared__ float hrev[2][1088];
    __shared__ float red[4][16];
    __shared__ float redf[16];
    __shared__ float red2[4][16];
    __shared__ float redf2[16];

    const int t = threadIdx.x;
    const int lane = t & 63, wid = t >> 6;
    const size_t b0 = (size_t)blockIdx.x * 4;

    for (int idx = t; idx < 2 * 1088; idx += 256)
        (&hrev[0][0])[idx] = ws[idx];
    __syncthreads();

    float acc[4][2][4];
    #pragma unroll
    for (int b = 0; b < 4; ++b)
        #pragma unroll
        for (int c = 0; c < 2; ++c)
            #pragma unroll
            for (int k = 0; k < 4; ++k) acc[b][c][k] = 0.f;

    #pragma unroll 1
    for (int i0 = 0; i0 < 64; i0 += 8) {
        const int q0 = 56 + 4 * t - i0;
        float r[2][12];
        #pragma unroll
        for (int c = 0; c < 2; ++c) {
            const float4* p = reinterpret_cast<const float4*>(&hrev[c][q0]);
            const float4 a0 = p[0], a1 = p[1], a2 = p[2];
            r[c][0] = a0.x; r[c][1] = a0.y; r[c][2]  = a0.z; r[c][3]  = a0.w;
            r[c][4] = a1.x; r[c][5] = a1.y; r[c][6]  = a1.z; r[c][7]  = a1.w;
            r[c][8] = a2.x; r[c][9] = a2.y; r[c][10] = a2.z; r[c][11] = a2.w;
        }
        #pragma unroll
        for (int b = 0; b < 4; ++b) {
            #pragma unroll
            for (int c = 0; c < 2; ++c) {
                const float* xp = values + ((b0 + b) * 2 + c) * 64 + i0;
                #pragma unroll
                for (int il = 0; il < 8; ++il) {
                    const float xv = xp[il];
                    #pragma unroll
                    for (int k = 0; k < 4; ++k)
                        acc[b][c][k] = fmaf(xv, r[c][7 - il + k], acc[b][c][k]);
                }
            }
        }
    }

    {
        float v16[16];
        #pragma unroll
        for (int b = 0; b < 4; ++b)
            #pragma unroll
            for (int c = 0; c < 2; ++c) {
                const float a0 = acc[b][c][0], a1 = acc[b][c][1];
                const float a2 = acc[b][c][2], a3 = acc[b][c][3];
                v16[(b * 2 + c) * 2]     = a0 + a1 + a2 + a3;
                v16[(b * 2 + c) * 2 + 1] = a0 * a0 + a1 * a1 + a2 * a2 + a3 * a3;
            }
        #pragma unroll
        for (int off = 32; off; off >>= 1)
            #pragma unroll
            for (int v = 0; v < 16; ++v)
                v16[v] += __shfl_xor(v16[v], off);
        if (lane == 0) {
            #pragma unroll
            for (int v = 0; v < 16; ++v) red[wid][v] = v16[v];
        }
    }
    __syncthreads();
    if (t < 16) redf[t] = red[0][t] + red[1][t] + red[2][t] + red[3][t];
    __syncthreads();

    const float4 g4  = *reinterpret_cast<const float4*>(&gamma[4 * t]);
    const float4 be4 = *reinterpret_cast<const float4*>(&beta[4 * t]);
    float sp_r[2][4];
    #pragma unroll
    for (int a = 0; a < 2; ++a) {
        const float4 s4 = *reinterpret_cast<const float4*>(&ws[2176 + a * 1024 + 4 * t]);
        sp_r[a][0] = s4.x; sp_r[a][1] = s4.y; sp_r[a][2] = s4.z; sp_r[a][3] = s4.w;
    }
    const float gk[4] = {g4.x, g4.y, g4.z, g4.w};
    const float bk[4] = {be4.x, be4.y, be4.z, be4.w};

    #pragma unroll
    for (int b = 0; b < 4; ++b)
        #pragma unroll
        for (int c = 0; c < 2; ++c) {
            const float sum = redf[(b * 2 + c) * 2];
            const float sq  = redf[(b * 2 + c) * 2 + 1];
            const float mu  = sum * (1.f / 1024.f);
            float var = sq * (1.f / 1024.f) - mu * mu;
            var = fmaxf(var, 0.f);
            const float rs = rsqrtf(var + LN_EPS);
            #pragma unroll
            for (int k = 0; k < 4; ++k)
                acc[b][c][k] = siluf((acc[b][c][k] - mu) * rs * gk[k] + bk[k]);
        }

    {
        float v16[16];
        #pragma unroll
        for (int b = 0; b < 4; ++b)
            #pragma unroll
            for (int a = 0; a < 2; ++a)
                #pragma unroll
                for (int c = 0; c < 2; ++c) {
                    float s = 0.f;
                    #pragma unroll
                    for (int k = 0; k < 4; ++k)
                        s += sgnf(acc[b][c][k]) * sgnf(acc[b][c][k] + sp_r[a][k]);
                    v16[b * 4 + a * 2 + c] = s;
                }
        #pragma unroll
        for (int off = 32; off; off >>= 1)
            #pragma unroll
            for (int v = 0; v < 16; ++v)
                v16[v] += __shfl_xor(v16[v], off);
        if (lane == 0) {
            #pragma unroll
            for (int v = 0; v < 16; ++v) red2[wid][v] = v16[v];
        }
    }
    __syncthreads();
    if (t < 16) redf2[t] = red2[0][t] + red2[1][t] + red2[2][t] + red2[3][t];
    __syncthreads();

    #pragma unroll
    for (int b = 0; b < 4; ++b) {
        #pragma unroll
        for (int a = 0; a < 2; ++a) {
            const float s0 = redf2[b * 4 + a * 2 + 0] * (1.f / 1024.f);
            const float s1 = redf2[b * 4 + a * 2 + 1] * (1.f / 1024.f);
            const float m  = fmaxf(s0, s1);
            const float e0 = __expf(s0 - m), e1 = __expf(s1 - m);
            const float inv = 1.f / (e0 + e1);
            const float p0 = e0 * inv, p1 = e1 * inv;
            float4 o;
            o.x = siluf((p0 * acc[b][0][0] + p1 * acc[b][1][0]) * sp_r[a][0]);
            o.y = siluf((p0 * acc[b][0][1] + p1 * acc[b][1][1]) * sp_r[a][1]);
            o.z = siluf((p0 * acc[b][0][2] + p1 * acc[b][1][2]) * sp_r[a][2]);
            o.w = siluf((p0 * acc[b][0][3] + p1 * acc[b][1][3]) * sp_r[a][3]);
            *reinterpret_cast<float4*>(out + ((b0 + b) * 2 + a) * 1024 + 4 * t) = o;
        }
    }
}

extern "C" void kernel_launch(void* const* d_in, const int* in_sizes, int n_in,
                              void* d_out, int out_size, void* d_ws, size_t ws_size,
                              hipStream_t stream) {
    const float* values  = (const float*)d_in[0];
    const float* h       = (const float*)d_in[1];
    const float* gamma   = (const float*)d_in[2];
    const float* beta    = (const float*)d_in[3];
    const float* symbols = (const float*)d_in[4];
    float* out = (float*)d_out;
    float* ws  = (float*)d_ws;

    const int B = in_sizes[0] / 128;   // 16384

    if (ws_size >= 794624) {
        // fast MFMA path
        hipLaunchKernelGGL(hd_prep_sp, dim3(1), dim3(256), 0, stream,
                           h, symbols, gamma, beta, ws);
        hipLaunchKernelGGL(hd_prep_bpack, dim3(256), dim3(256), 0, stream, h, ws);
        hipLaunchKernelGGL(hd_main_mfma, dim3(B / 16), dim3(1024), 0, stream,
                           values, gamma, beta, ws, out);
    } else {
        // scalar fallback (R2-proven)
        hipLaunchKernelGGL(hd_prep_scalar, dim3(1), dim3(256), 0, stream,
                           h, symbols, gamma, beta, ws);
        hipLaunchKernelGGL(hd_main_scalar, dim3(B / 4), dim3(256), 0, stream,
                           values, gamma, beta, ws, out);
    }
}

// Round 15
// 107.482 us; speedup vs baseline: 1.0880x; 1.0880x over previous
//
#include <hip/hip_runtime.h>

#define LN_EPS 1e-3f

typedef __attribute__((ext_vector_type(8))) short bf16x8;
typedef __attribute__((ext_vector_type(4))) float f32x4;

static __device__ __forceinline__ float sgnf(float x) {
    return (x > 0.f) ? 1.f : ((x < 0.f) ? -1.f : 0.f);
}
// silu via single-instruction v_rcp_f32: denominator > 0 so sign(silu(x)) == sign(x).
static __device__ __forceinline__ float siluf(float x) {
    return x * __builtin_amdgcn_rcpf(1.f + __expf(-x));
}

// round-to-nearest-even fp32 -> bf16 bits
static __device__ __forceinline__ unsigned short f2bf(float f) {
    unsigned int u = __float_as_uint(f);
    return (unsigned short)((u + 0x7fffu + ((u >> 16) & 1u)) >> 16);
}
static __device__ __forceinline__ float bf2f(unsigned short s) {
    return __uint_as_float(((unsigned int)s) << 16);
}
// exact 3-way bf16 split: v = hi + mid + lo (+ O(2^-27) rel)
static __device__ __forceinline__ void split3(float v, unsigned short& hi,
                                              unsigned short& mid, unsigned short& lo) {
    hi = f2bf(v);
    const float r1 = v - bf2f(hi);       // exact (Sterbenz)
    mid = f2bf(r1);
    const float r2 = r1 - bf2f(mid);     // exact
    lo = f2bf(r2);
}

// ================= FAST PATH (MFMA) — requires ws_size >= 794624 =================
// ws layout (bytes):
//   [0, 786432)          Bpack: bf16 H^T fragments, 3-way split, part-major (coalesced)
//     bf16x8 index = ((c*2+ks)*64 + ntg)*192 + part*64 + lane
//   [786432, 794624)     sp[2][1024] fp32   (float offset 196608)
#define SPOFF 196608

// ---------------- fast prep 1: sp ----------------
__global__ __launch_bounds__(256) void hd_prep_sp(
    const float* __restrict__ h, const float* __restrict__ symbols,
    const float* __restrict__ gamma, const float* __restrict__ beta,
    float* __restrict__ ws)
{
    __shared__ float h_pad[2][1088];
    __shared__ float x_s[2][64];
    __shared__ float red[4][2];
    const int t = threadIdx.x;

    for (int idx = t; idx < 2 * 1088; idx += 256) {
        const int c = idx / 1088, j = idx - c * 1088;
        float v = 0.f;
        if (j >= 63 && j <= 1023) v = h[c * 961 + (j - 63)];
        h_pad[c][j] = v;
    }
    if (t < 128) x_s[t >> 6][t & 63] = symbols[t];
    __syncthreads();

    const int c = t >> 7, tt = t & 127;
    const int lane = t & 63, wid = t >> 6;
    const int jbase = 1023 - tt;

    float acc[8];
    #pragma unroll
    for (int k = 0; k < 8; ++k) acc[k] = 0.f;

    #pragma unroll 8
    for (int i = 0; i < 64; ++i) {
        const float xv = x_s[c][i];
        #pragma unroll
        for (int k = 0; k < 8; ++k)
            acc[k] = fmaf(xv, h_pad[c][jbase + i - 128 * k], acc[k]);
    }

    float ps = 0.f, pq = 0.f;
    #pragma unroll
    for (int k = 0; k < 8; ++k) { ps += acc[k]; pq += acc[k] * acc[k]; }
    #pragma unroll
    for (int off = 32; off; off >>= 1) {
        ps += __shfl_xor(ps, off);
        pq += __shfl_xor(pq, off);
    }
    if (lane == 0) { red[wid][0] = ps; red[wid][1] = pq; }
    __syncthreads();

    const float sum = red[2 * c][0] + red[2 * c + 1][0];
    const float sq  = red[2 * c][1] + red[2 * c + 1][1];
    const float mu  = sum * (1.f / 1024.f);
    float var = sq * (1.f / 1024.f) - mu * mu;
    var = fmaxf(var, 0.f);
    const float rs = rsqrtf(var + LN_EPS);

    #pragma unroll
    for (int k = 0; k < 8; ++k) {
        const int d = tt + 128 * k;
        const float ln = (acc[k] - mu) * rs * gamma[d] + beta[d];
        ws[SPOFF + c * 1024 + d] = siluf(ln);
    }
}

// ---------------- fast prep 2: Bpack (part-major layout) ----------------
__global__ __launch_bounds__(256) void hd_prep_bpack(
    const float* __restrict__ h, float* __restrict__ ws)
{
    unsigned short* Bp = (unsigned short*)ws;
    const int total = 2 * 2 * 64 * 64 * 8;   // 131072 positions, 3 parts each
    for (int e = blockIdx.x * 256 + threadIdx.x; e < total; e += gridDim.x * 256) {
        const int j   = e & 7;
        const int l   = (e >> 3) & 63;
        const int ntg = (e >> 9) & 63;
        const int ks  = (e >> 15) & 1;
        const int c   = (e >> 16) & 1;
        const int H = 1023 - (16 * ntg + (l & 15)) + 32 * ks + 8 * (l >> 4) + j;
        float v = 0.f;
        if (H >= 63 && H <= 1023) v = h[c * 961 + (H - 63)];
        unsigned short hi, mid, lo;
        split3(v, hi, mid, lo);
        const int T = (c * 2 + ks) * 64 + ntg;
        Bp[((T * 192 +   0 + l)) * 8 + j] = hi;
        Bp[((T * 192 +  64 + l)) * 8 + j] = mid;
        Bp[((T * 192 + 128 + l)) * 8 + j] = lo;
    }
}

// ---------------- fast main: 1024 thr (16 waves), wave w -> d in [64w, 64w+64) ----------------
__global__ __launch_bounds__(1024, 4) void hd_main_mfma(
    const float* __restrict__ values,
    const float* __restrict__ gamma, const float* __restrict__ beta,
    const float* __restrict__ ws, float* __restrict__ out)
{
    __shared__ __align__(16) unsigned short a_lds[2][2][3][16][40];
    __shared__ float stats[16][4][2][4][2];  // [wave][g][c][r][sum,sq]
    __shared__ int   sred [16][4][2][4][2];  // [wave][g][c][r][a]
    __shared__ float statsF[64];             // [g][c][r][s]
    __shared__ int   sredF [64];             // [g][c][r][a]
    __shared__ float otile[16][4][72];       // per-WAVE store tile

    const int t = threadIdx.x;
    const int w = t >> 6, l = t & 63;
    const int g = l >> 4, q = l & 15;
    const int b0 = blockIdx.x * 16;

    // ---- cooperative A-fragment prep: 2048 x-values, thread t split3's values 2t, 2t+1
    {
        const float2 xv2 = *reinterpret_cast<const float2*>(
            values + (size_t)b0 * 128 + 2 * t);
        #pragma unroll
        for (int u = 0; u < 2; ++u) {
            const int v  = 2 * t + u;
            const int q_ = v >> 7, c_ = (v >> 6) & 1, k_ = v & 63;
            const int ks_ = k_ >> 5, gj = k_ & 31;
            unsigned short hb, mb, lb;
            split3(u == 0 ? xv2.x : xv2.y, hb, mb, lb);
            a_lds[c_][ks_][0][q_][gj] = hb;
            a_lds[c_][ks_][1][q_][gj] = mb;
            a_lds[c_][ks_][2][q_][gj] = lb;
        }
    }
    __syncthreads();

    // ---- A fragments from LDS (bit-identical to per-thread split)
    bf16x8 ahi[2][2], amd_[2][2], alo[2][2];
    #pragma unroll
    for (int c = 0; c < 2; ++c)
        #pragma unroll
        for (int ks = 0; ks < 2; ++ks) {
            ahi[c][ks]  = *reinterpret_cast<const bf16x8*>(&a_lds[c][ks][0][q][8 * g]);
            amd_[c][ks] = *reinterpret_cast<const bf16x8*>(&a_lds[c][ks][1][q][8 * g]);
            alo[c][ks]  = *reinterpret_cast<const bf16x8*>(&a_lds[c][ks][2][q][8 * g]);
        }

    // ---- MFMA (R10 body)
    const bf16x8* Bv = reinterpret_cast<const bf16x8*>(ws) + l;
    f32x4 acc[2][4];
    #pragma unroll
    for (int c = 0; c < 2; ++c)
        #pragma unroll
        for (int nt = 0; nt < 4; ++nt)
            acc[c][nt] = (f32x4){0.f, 0.f, 0.f, 0.f};

    __builtin_amdgcn_s_setprio(1);
    #pragma unroll
    for (int nt = 0; nt < 4; ++nt) {
        const int ntg = w * 4 + nt;
        #pragma unroll
        for (int c = 0; c < 2; ++c) {
            f32x4 ts = {0.f, 0.f, 0.f, 0.f};
            f32x4 tm = {0.f, 0.f, 0.f, 0.f};
            f32x4 th = {0.f, 0.f, 0.f, 0.f};
            #pragma unroll
            for (int ks = 0; ks < 2; ++ks) {
                const bf16x8* p = Bv + (size_t)((c * 2 + ks) * 64 + ntg) * 192;
                const bf16x8 bh = p[0], bm = p[64], bl = p[128];
                ts = __builtin_amdgcn_mfma_f32_16x16x32_bf16(amd_[c][ks], bl, ts, 0, 0, 0);
                ts = __builtin_amdgcn_mfma_f32_16x16x32_bf16(alo[c][ks], bm, ts, 0, 0, 0);
                ts = __builtin_amdgcn_mfma_f32_16x16x32_bf16(ahi[c][ks], bl, ts, 0, 0, 0);
                ts = __builtin_amdgcn_mfma_f32_16x16x32_bf16(amd_[c][ks], bm, ts, 0, 0, 0);
                ts = __builtin_amdgcn_mfma_f32_16x16x32_bf16(alo[c][ks], bh, ts, 0, 0, 0);
                tm = __builtin_amdgcn_mfma_f32_16x16x32_bf16(ahi[c][ks], bm, tm, 0, 0, 0);
                tm = __builtin_amdgcn_mfma_f32_16x16x32_bf16(amd_[c][ks], bh, tm, 0, 0, 0);
                th = __builtin_amdgcn_mfma_f32_16x16x32_bf16(ahi[c][ks], bh, th, 0, 0, 0);
            }
            #pragma unroll
            for (int r = 0; r < 4; ++r)
                acc[c][nt][r] = (ts[r] + tm[r]) + th[r];
        }
    }
    __builtin_amdgcn_s_setprio(0);

    // ---- LN stats: per (w,g,c,r) partial over q (shfl) -> LDS -> 2-stage block reduce
    {
        float s_[2][4], q_[2][4];
        #pragma unroll
        for (int c = 0; c < 2; ++c)
            #pragma unroll
            for (int r = 0; r < 4; ++r) { s_[c][r] = 0.f; q_[c][r] = 0.f; }
        #pragma unroll
        for (int c = 0; c < 2; ++c)
            #pragma unroll
            for (int nt = 0; nt < 4; ++nt)
                #pragma unroll
                for (int r = 0; r < 4; ++r) {
                    const float v = acc[c][nt][r];
                    s_[c][r] += v;
                    q_[c][r] += v * v;
                }
        #pragma unroll
        for (int off = 1; off < 16; off <<= 1)
            #pragma unroll
            for (int c = 0; c < 2; ++c)
                #pragma unroll
                for (int r = 0; r < 4; ++r) {
                    s_[c][r] += __shfl_xor(s_[c][r], off);
                    q_[c][r] += __shfl_xor(q_[c][r], off);
                }
        if (q == 0) {
            #pragma unroll
            for (int c = 0; c < 2; ++c)
                #pragma unroll
                for (int r = 0; r < 4; ++r) {
                    stats[w][g][c][r][0] = s_[c][r];
                    stats[w][g][c][r][1] = q_[c][r];
                }
        }
    }
    __syncthreads();
    if (t < 64) {   // t = ((g*2+c)*4+r)*2+s
        const int gg = t >> 4, cc = (t >> 3) & 1, rr = (t >> 1) & 3, ss = t & 1;
        float S = 0.f;
        #pragma unroll
        for (int w2 = 0; w2 < 16; ++w2) S += stats[w2][gg][cc][rr][ss];
        statsF[t] = S;
    }
    __syncthreads();

    float mu_[2][4], rs_[2][4];
    #pragma unroll
    for (int c = 0; c < 2; ++c)
        #pragma unroll
        for (int r = 0; r < 4; ++r) {
            const float S = statsF[((g * 2 + c) * 4 + r) * 2 + 0];
            const float Q = statsF[((g * 2 + c) * 4 + r) * 2 + 1];
            const float mu = S * (1.f / 1024.f);
            float var = Q * (1.f / 1024.f) - mu * mu;
            var = fmaxf(var, 0.f);
            mu_[c][r] = mu;
            rs_[c][r] = rsqrtf(var + LN_EPS);
        }

    // ---- vp = silu(LN(y)) in-place
    const int dbase = w * 64 + q;
    #pragma unroll
    for (int nt = 0; nt < 4; ++nt) {
        const int d = dbase + 16 * nt;
        const float gam = gamma[d];
        const float bet = beta[d];
        #pragma unroll
        for (int c = 0; c < 2; ++c)
            #pragma unroll
            for (int r = 0; r < 4; ++r)
                acc[c][nt][r] = siluf((acc[c][nt][r] - mu_[c][r]) * rs_[c][r] * gam + bet);
    }

    // ---- sp cached once (reused by sign-count and epilogue)
    float spv[2][4];
    #pragma unroll
    for (int nt = 0; nt < 4; ++nt) {
        const int d = dbase + 16 * nt;
        spv[0][nt] = ws[SPOFF + d];
        spv[1][nt] = ws[SPOFF + 1024 + d];
    }

    // ---- S sign-counts (UNPACKED, R10 form — A/B test vs R12's packed variant)
    int cnt[2][4][2];
    #pragma unroll
    for (int c = 0; c < 2; ++c)
        #pragma unroll
        for (int r = 0; r < 4; ++r) { cnt[c][r][0] = 0; cnt[c][r][1] = 0; }
    #pragma unroll
    for (int nt = 0; nt < 4; ++nt) {
        #pragma unroll
        for (int c = 0; c < 2; ++c)
            #pragma unroll
            for (int r = 0; r < 4; ++r) {
                const float v = acc[c][nt][r];
                const unsigned int iv = __float_as_uint(v);
                cnt[c][r][0] += (int)((iv ^ __float_as_uint(v + spv[0][nt])) >> 31);
                cnt[c][r][1] += (int)((iv ^ __float_as_uint(v + spv[1][nt])) >> 31);
            }
    }
    #pragma unroll
    for (int off = 1; off < 16; off <<= 1)
        #pragma unroll
        for (int c = 0; c < 2; ++c)
            #pragma unroll
            for (int r = 0; r < 4; ++r) {
                cnt[c][r][0] += __shfl_xor(cnt[c][r][0], off);
                cnt[c][r][1] += __shfl_xor(cnt[c][r][1], off);
            }
    if (q == 0) {
        #pragma unroll
        for (int c = 0; c < 2; ++c)
            #pragma unroll
            for (int r = 0; r < 4; ++r) {
                sred[w][g][c][r][0] = cnt[c][r][0];
                sred[w][g][c][r][1] = cnt[c][r][1];
            }
    }
    __syncthreads();
    if (t < 64) {   // t = ((g*2+c)*4+r)*2+a
        const int gg = t >> 4, cc = (t >> 3) & 1, rr = (t >> 1) & 3, aa = t & 1;
        int S = 0;
        #pragma unroll
        for (int w2 = 0; w2 < 16; ++w2) S += sred[w2][gg][cc][rr][aa];
        sredF[t] = S;
    }
    __syncthreads();

    // ---- softmax over c
    float p0_[4][2], p1_[4][2];
    #pragma unroll
    for (int r = 0; r < 4; ++r)
        #pragma unroll
        for (int a = 0; a < 2; ++a) {
            const int t0 = sredF[((g * 2 + 0) * 4 + r) * 2 + a];
            const int t1 = sredF[((g * 2 + 1) * 4 + r) * 2 + a];
            const float S0 = 1.f - 2.f * (float)t0 * (1.f / 1024.f);
            const float S1 = 1.f - 2.f * (float)t1 * (1.f / 1024.f);
            const float m  = fmaxf(S0, S1);
            const float e0 = __expf(S0 - m), e1 = __expf(S1 - m);
            const float inv = __builtin_amdgcn_rcpf(e0 + e1);
            p0_[r][a] = e0 * inv;
            p1_[r][a] = e1 * inv;
        }

    // ---- attn + silu + store. otile is wave-private; DS ops in-order per wave.
    const int g2 = l >> 4, qq = l & 15;
    #pragma unroll
    for (int a = 0; a < 2; ++a) {
        #pragma unroll
        for (int r = 0; r < 4; ++r) {
            #pragma unroll
            for (int nt = 0; nt < 4; ++nt) {
                const float attn = p0_[r][a] * acc[0][nt][r] + p1_[r][a] * acc[1][nt][r];
                otile[w][g][16 * nt + q] = siluf(attn * spv[a][nt]);
            }
            __builtin_amdgcn_wave_barrier();
            const float4 v4 = *reinterpret_cast<const float4*>(&otile[w][g2][4 * qq]);
            *reinterpret_cast<float4*>(
                out + ((size_t)(b0 + 4 * g2 + r) * 2 + a) * 1024 + 64 * w + 4 * qq) = v4;
            __builtin_amdgcn_wave_barrier();
        }
    }
}

// ================= FALLBACK PATH (scalar, R2-proven) =================
// ws floats: [0,2176) hrev ; [2176,4224) sp
__global__ __launch_bounds__(256) void hd_prep_scalar(
    const float* __restrict__ h, const float* __restrict__ symbols,
    const float* __restrict__ gamma, const float* __restrict__ beta,
    float* __restrict__ ws)
{
    __shared__ float h_pad[2][1088];
    __shared__ float x_s[2][64];
    __shared__ float red[4][2];
    const int t = threadIdx.x;

    for (int idx = t; idx < 2 * 1088; idx += 256) {
        const int c = idx / 1088, j = idx - c * 1088;
        float v = 0.f;
        if (j >= 63 && j <= 1023) v = h[c * 961 + (j - 63)];
        h_pad[c][j] = v;
        const int src = 1086 - j;
        float vr = 0.f;
        if (src >= 63 && src <= 1023) vr = h[c * 961 + (src - 63)];
        ws[c * 1088 + j] = vr;
    }
    if (t < 128) x_s[t >> 6][t & 63] = symbols[t];
    __syncthreads();

    const int c = t >> 7, tt = t & 127;
    const int lane = t & 63, wid = t >> 6;
    const int jbase = 1023 - tt;

    float acc[8];
    #pragma unroll
    for (int k = 0; k < 8; ++k) acc[k] = 0.f;

    #pragma unroll 8
    for (int i = 0; i < 64; ++i) {
        const float xv = x_s[c][i];
        #pragma unroll
        for (int k = 0; k < 8; ++k)
            acc[k] = fmaf(xv, h_pad[c][jbase + i - 128 * k], acc[k]);
    }

    float ps = 0.f, pq = 0.f;
    #pragma unroll
    for (int k = 0; k < 8; ++k) { ps += acc[k]; pq += acc[k] * acc[k]; }
    #pragma unroll
    for (int off = 32; off; off >>= 1) {
        ps += __shfl_xor(ps, off);
        pq += __shfl_xor(pq, off);
    }
    if (lane == 0) { red[wid][0] = ps; red[wid][1] = pq; }
    __syncthreads();

    const float sum = red[2 * c][0] + red[2 * c + 1][0];
    const float sq  = red[2 * c][1] + red[2 * c + 1][1];
    const float mu  = sum * (1.f / 1024.f);
    float var = sq * (1.f / 1024.f) - mu * mu;
    var = fmaxf(var, 0.f);
    const float rs = rsqrtf(var + LN_EPS);

    #pragma unroll
    for (int k = 0; k < 8; ++k) {
        const int d = tt + 128 * k;
        const float ln = (acc[k] - mu) * rs * gamma[d] + beta[d];
        ws[2176 + c * 1024 + d] = siluf(ln);
    }
}

__global__ __launch_bounds__(256, 4) void hd_main_scalar(
    const float* __restrict__ values,
    const float* __restrict__ gamma, const float* __restrict__ beta,
    const float* __restrict__ ws, float* __restrict__ out)
{
    __shared__ float hrev[2][1088];
    __shared__ float red[4][16];
    __shared__ float redf[16];
    __shared__ float red2[4][16];
    __shared__ float redf2[16];

    const int t = threadIdx.x;
    const int lane = t & 63, wid = t >> 6;
    const size_t b0 = (size_t)blockIdx.x * 4;

    for (int idx = t; idx < 2 * 1088; idx += 256)
        (&hrev[0][0])[idx] = ws[idx];
    __syncthreads();

    float acc[4][2][4];
    #pragma unroll
    for (int b = 0; b < 4; ++b)
        #pragma unroll
        for (int c = 0; c < 2; ++c)
            #pragma unroll
            for (int k = 0; k < 4; ++k) acc[b][c][k] = 0.f;

    #pragma unroll 1
    for (int i0 = 0; i0 < 64; i0 += 8) {
        const int q0 = 56 + 4 * t - i0;
        float r[2][12];
        #pragma unroll
        for (int c = 0; c < 2; ++c) {
            const float4* p = reinterpret_cast<const float4*>(&hrev[c][q0]);
            const float4 a0 = p[0], a1 = p[1], a2 = p[2];
            r[c][0] = a0.x; r[c][1] = a0.y; r[c][2]  = a0.z; r[c][3]  = a0.w;
            r[c][4] = a1.x; r[c][5] = a1.y; r[c][6]  = a1.z; r[c][7]  = a1.w;
            r[c][8] = a2.x; r[c][9] = a2.y; r[c][10] = a2.z; r[c][11] = a2.w;
        }
        #pragma unroll
        for (int b = 0; b < 4; ++b) {
            #pragma unroll
            for (int c = 0; c < 2; ++c) {
                const float* xp = values + ((b0 + b) * 2 + c) * 64 + i0;
                #pragma unroll
                for (int il = 0; il < 8; ++il) {
                    const float xv = xp[il];
                    #pragma unroll
                    for (int k = 0; k < 4; ++k)
                        acc[b][c][k] = fmaf(xv, r[c][7 - il + k], acc[b][c][k]);
                }
            }
        }
    }

    {
        float v16[16];
        #pragma unroll
        for (int b = 0; b < 4; ++b)
            #pragma unroll
            for (int c = 0; c < 2; ++c) {
                const float a0 = acc[b][c][0], a1 = acc[b][c][1];
                const float a2 = acc[b][c][2], a3 = acc[b][c][3];
                v16[(b * 2 + c) * 2]     = a0 + a1 + a2 + a3;
                v16[(b * 2 + c) * 2 + 1] = a0 * a0 + a1 * a1 + a2 * a2 + a3 * a3;
            }
        #pragma unroll
        for (int off = 32; off; off >>= 1)
            #pragma unroll
            for (int v = 0; v < 16; ++v)
                v16[v] += __shfl_xor(v16[v], off);
        if (lane == 0) {
            #pragma unroll
            for (int v = 0; v < 16; ++v) red[wid][v] = v16[v];
        }
    }
    __syncthreads();
    if (t < 16) redf[t] = red[0][t] + red[1][t] + red[2][t] + red[3][t];
    __syncthreads();

    const float4 g4  = *reinterpret_cast<const float4*>(&gamma[4 * t]);
    const float4 be4 = *reinterpret_cast<const float4*>(&beta[4 * t]);
    float sp_r[2][4];
    #pragma unroll
    for (int a = 0; a < 2; ++a) {
        const float4 s4 = *reinterpret_cast<const float4*>(&ws[2176 + a * 1024 + 4 * t]);
        sp_r[a][0] = s4.x; sp_r[a][1] = s4.y; sp_r[a][2] = s4.z; sp_r[a][3] = s4.w;
    }
    const float gk[4] = {g4.x, g4.y, g4.z, g4.w};
    const float bk[4] = {be4.x, be4.y, be4.z, be4.w};

    #pragma unroll
    for (int b = 0; b < 4; ++b)
        #pragma unroll
        for (int c = 0; c < 2; ++c) {
            const float sum = redf[(b * 2 + c) * 2];
            const float sq  = redf[(b * 2 + c) * 2 + 1];
            const float mu  = sum * (1.f / 1024.f);
            float var = sq * (1.f / 1024.f) - mu * mu;
            var = fmaxf(var, 0.f);
            const float rs = rsqrtf(var + LN_EPS);
            #pragma unroll
            for (int k = 0; k < 4; ++k)
                acc[b][c][k] = siluf((acc[b][c][k] - mu) * rs * gk[k] + bk[k]);
        }

    {
        float v16[16];
        #pragma unroll
        for (int b = 0; b < 4; ++b)
            #pragma unroll
            for (int a = 0; a < 2; ++a)
                #pragma unroll
                for (int c = 0; c < 2; ++c) {
                    float s = 0.f;
                    #pragma unroll
                    for (int k = 0; k < 4; ++k)
                        s += sgnf(acc[b][c][k]) * sgnf(acc[b][c][k] + sp_r[a][k]);
                    v16[b * 4 + a * 2 + c] = s;
                }
        #pragma unroll
        for (int off = 32; off; off >>= 1)
            #pragma unroll
            for (int v = 0; v < 16; ++v)
                v16[v] += __shfl_xor(v16[v], off);
        if (lane == 0) {
            #pragma unroll
            for (int v = 0; v < 16; ++v) red2[wid][v] = v16[v];
        }
    }
    __syncthreads();
    if (t < 16) redf2[t] = red2[0][t] + red2[1][t] + red2[2][t] + red2[3][t];
    __syncthreads();

    #pragma unroll
    for (int b = 0; b < 4; ++b) {
        #pragma unroll
        for (int a = 0; a < 2; ++a) {
            const float s0 = redf2[b * 4 + a * 2 + 0] * (1.f / 1024.f);
            const float s1 = redf2[b * 4 + a * 2 + 1] * (1.f / 1024.f);
            const float m  = fmaxf(s0, s1);
            const float e0 = __expf(s0 - m), e1 = __expf(s1 - m);
            const float inv = 1.f / (e0 + e1);
            const float p0 = e0 * inv, p1 = e1 * inv;
            float4 o;
            o.x = siluf((p0 * acc[b][0][0] + p1 * acc[b][1][0]) * sp_r[a][0]);
            o.y = siluf((p0 * acc[b][0][1] + p1 * acc[b][1][1]) * sp_r[a][1]);
            o.z = siluf((p0 * acc[b][0][2] + p1 * acc[b][1][2]) * sp_r[a][2]);
            o.w = siluf((p0 * acc[b][0][3] + p1 * acc[b][1][3]) * sp_r[a][3]);
            *reinterpret_cast<float4*>(out + ((b0 + b) * 2 + a) * 1024 + 4 * t) = o;
        }
    }
}

extern "C" void kernel_launch(void* const* d_in, const int* in_sizes, int n_in,
                              void* d_out, int out_size, void* d_ws, size_t ws_size,
                              hipStream_t stream) {
    const float* values  = (const float*)d_in[0];
    const float* h       = (const float*)d_in[1];
    const float* gamma   = (const float*)d_in[2];
    const float* beta    = (const float*)d_in[3];
    const float* symbols = (const float*)d_in[4];
    float* out = (float*)d_out;
    float* ws  = (float*)d_ws;

    const int B = in_sizes[0] / 128;   // 16384

    if (ws_size >= 794624) {
        // fast MFMA path
        hipLaunchKernelGGL(hd_prep_sp, dim3(1), dim3(256), 0, stream,
                           h, symbols, gamma, beta, ws);
        hipLaunchKernelGGL(hd_prep_bpack, dim3(256), dim3(256), 0, stream, h, ws);
        hipLaunchKernelGGL(hd_main_mfma, dim3(B / 16), dim3(1024), 0, stream,
                           values, gamma, beta, ws, out);
    } else {
        // scalar fallback (R2-proven)
        hipLaunchKernelGGL(hd_prep_scalar, dim3(1), dim3(256), 0, stream,
                           h, symbols, gamma, beta, ws);
        hipLaunchKernelGGL(hd_main_scalar, dim3(B / 4), dim3(256), 0, stream,
                           values, gamma, beta, ws, out);
    }
}

// Round 16
// 107.427 us; speedup vs baseline: 1.0885x; 1.0005x over previous
//
#include <hip/hip_runtime.h>

#define LN_EPS 1e-3f

typedef __attribute__((ext_vector_type(8))) short bf16x8;
typedef __attribute__((ext_vector_type(4))) float f32x4;

static __device__ __forceinline__ float sgnf(float x) {
    return (x > 0.f) ? 1.f : ((x < 0.f) ? -1.f : 0.f);
}
// silu via single-instruction v_rcp_f32: denominator > 0 so sign(silu(x)) == sign(x).
static __device__ __forceinline__ float siluf(float x) {
    return x * __builtin_amdgcn_rcpf(1.f + __expf(-x));
}

// round-to-nearest-even fp32 -> bf16 bits
static __device__ __forceinline__ unsigned short f2bf(float f) {
    unsigned int u = __float_as_uint(f);
    return (unsigned short)((u + 0x7fffu + ((u >> 16) & 1u)) >> 16);
}
static __device__ __forceinline__ float bf2f(unsigned short s) {
    return __uint_as_float(((unsigned int)s) << 16);
}
// exact 3-way bf16 split: v = hi + mid + lo (+ O(2^-27) rel)
static __device__ __forceinline__ void split3(float v, unsigned short& hi,
                                              unsigned short& mid, unsigned short& lo) {
    hi = f2bf(v);
    const float r1 = v - bf2f(hi);       // exact (Sterbenz)
    mid = f2bf(r1);
    const float r2 = r1 - bf2f(mid);     // exact
    lo = f2bf(r2);
}

// ================= FAST PATH (MFMA) — requires ws_size >= 794624 =================
// ws layout (bytes):
//   [0, 786432)          Bpack: bf16 H^T fragments, 3-way split, part-major (coalesced)
//     bf16x8 index = ((c*2+ks)*64 + ntg)*192 + part*64 + lane
//   [786432, 794624)     sp[2][1024] fp32   (float offset 196608)
#define SPOFF 196608

// ---------------- fast prep 1: sp ----------------
__global__ __launch_bounds__(256) void hd_prep_sp(
    const float* __restrict__ h, const float* __restrict__ symbols,
    const float* __restrict__ gamma, const float* __restrict__ beta,
    float* __restrict__ ws)
{
    __shared__ float h_pad[2][1088];
    __shared__ float x_s[2][64];
    __shared__ float red[4][2];
    const int t = threadIdx.x;

    for (int idx = t; idx < 2 * 1088; idx += 256) {
        const int c = idx / 1088, j = idx - c * 1088;
        float v = 0.f;
        if (j >= 63 && j <= 1023) v = h[c * 961 + (j - 63)];
        h_pad[c][j] = v;
    }
    if (t < 128) x_s[t >> 6][t & 63] = symbols[t];
    __syncthreads();

    const int c = t >> 7, tt = t & 127;
    const int lane = t & 63, wid = t >> 6;
    const int jbase = 1023 - tt;

    float acc[8];
    #pragma unroll
    for (int k = 0; k < 8; ++k) acc[k] = 0.f;

    #pragma unroll 8
    for (int i = 0; i < 64; ++i) {
        const float xv = x_s[c][i];
        #pragma unroll
        for (int k = 0; k < 8; ++k)
            acc[k] = fmaf(xv, h_pad[c][jbase + i - 128 * k], acc[k]);
    }

    float ps = 0.f, pq = 0.f;
    #pragma unroll
    for (int k = 0; k < 8; ++k) { ps += acc[k]; pq += acc[k] * acc[k]; }
    #pragma unroll
    for (int off = 32; off; off >>= 1) {
        ps += __shfl_xor(ps, off);
        pq += __shfl_xor(pq, off);
    }
    if (lane == 0) { red[wid][0] = ps; red[wid][1] = pq; }
    __syncthreads();

    const float sum = red[2 * c][0] + red[2 * c + 1][0];
    const float sq  = red[2 * c][1] + red[2 * c + 1][1];
    const float mu  = sum * (1.f / 1024.f);
    float var = sq * (1.f / 1024.f) - mu * mu;
    var = fmaxf(var, 0.f);
    const float rs = rsqrtf(var + LN_EPS);

    #pragma unroll
    for (int k = 0; k < 8; ++k) {
        const int d = tt + 128 * k;
        const float ln = (acc[k] - mu) * rs * gamma[d] + beta[d];
        ws[SPOFF + c * 1024 + d] = siluf(ln);
    }
}

// ---------------- fast prep 2: Bpack (part-major layout) ----------------
__global__ __launch_bounds__(256) void hd_prep_bpack(
    const float* __restrict__ h, float* __restrict__ ws)
{
    unsigned short* Bp = (unsigned short*)ws;
    const int total = 2 * 2 * 64 * 64 * 8;   // 131072 positions, 3 parts each
    for (int e = blockIdx.x * 256 + threadIdx.x; e < total; e += gridDim.x * 256) {
        const int j   = e & 7;
        const int l   = (e >> 3) & 63;
        const int ntg = (e >> 9) & 63;
        const int ks  = (e >> 15) & 1;
        const int c   = (e >> 16) & 1;
        const int H = 1023 - (16 * ntg + (l & 15)) + 32 * ks + 8 * (l >> 4) + j;
        float v = 0.f;
        if (H >= 63 && H <= 1023) v = h[c * 961 + (H - 63)];
        unsigned short hi, mid, lo;
        split3(v, hi, mid, lo);
        const int T = (c * 2 + ks) * 64 + ntg;
        Bp[((T * 192 +   0 + l)) * 8 + j] = hi;
        Bp[((T * 192 +  64 + l)) * 8 + j] = mid;
        Bp[((T * 192 + 128 + l)) * 8 + j] = lo;
    }
}

// ---------------- fast main: 1024 thr (16 waves), wave w -> d in [64w, 64w+64) ----------------
__global__ __launch_bounds__(1024, 4) void hd_main_mfma(
    const float* __restrict__ values,
    const float* __restrict__ gamma, const float* __restrict__ beta,
    const float* __restrict__ ws, float* __restrict__ out)
{
    __shared__ __align__(16) unsigned short a_lds[2][2][3][16][40];
    __shared__ float stats[16][4][2][4][2];  // [wave][g][c][r][sum,sq]
    __shared__ float statsF[64];             // [g][c][r][s]
    __shared__ int   sredF [64];             // [g][c][r][a] — atomic accumulator
    __shared__ float otile[16][4][72];       // per-WAVE store tile

    const int t = threadIdx.x;
    const int w = t >> 6, l = t & 63;
    const int g = l >> 4, q = l & 15;
    const int b0 = blockIdx.x * 16;

    // zero the sign-count accumulator before the first barrier
    if (t < 64) sredF[t] = 0;

    // ---- cooperative A-fragment prep: 2048 x-values, thread t split3's values 2t, 2t+1
    {
        const float2 xv2 = *reinterpret_cast<const float2*>(
            values + (size_t)b0 * 128 + 2 * t);
        #pragma unroll
        for (int u = 0; u < 2; ++u) {
            const int v  = 2 * t + u;
            const int q_ = v >> 7, c_ = (v >> 6) & 1, k_ = v & 63;
            const int ks_ = k_ >> 5, gj = k_ & 31;
            unsigned short hb, mb, lb;
            split3(u == 0 ? xv2.x : xv2.y, hb, mb, lb);
            a_lds[c_][ks_][0][q_][gj] = hb;
            a_lds[c_][ks_][1][q_][gj] = mb;
            a_lds[c_][ks_][2][q_][gj] = lb;
        }
    }
    __syncthreads();

    // ---- A fragments from LDS (bit-identical to per-thread split)
    bf16x8 ahi[2][2], amd_[2][2], alo[2][2];
    #pragma unroll
    for (int c = 0; c < 2; ++c)
        #pragma unroll
        for (int ks = 0; ks < 2; ++ks) {
            ahi[c][ks]  = *reinterpret_cast<const bf16x8*>(&a_lds[c][ks][0][q][8 * g]);
            amd_[c][ks] = *reinterpret_cast<const bf16x8*>(&a_lds[c][ks][1][q][8 * g]);
            alo[c][ks]  = *reinterpret_cast<const bf16x8*>(&a_lds[c][ks][2][q][8 * g]);
        }

    // ---- MFMA (R10 body)
    const bf16x8* Bv = reinterpret_cast<const bf16x8*>(ws) + l;
    f32x4 acc[2][4];
    #pragma unroll
    for (int c = 0; c < 2; ++c)
        #pragma unroll
        for (int nt = 0; nt < 4; ++nt)
            acc[c][nt] = (f32x4){0.f, 0.f, 0.f, 0.f};

    __builtin_amdgcn_s_setprio(1);
    #pragma unroll
    for (int nt = 0; nt < 4; ++nt) {
        const int ntg = w * 4 + nt;
        #pragma unroll
        for (int c = 0; c < 2; ++c) {
            f32x4 ts = {0.f, 0.f, 0.f, 0.f};
            f32x4 tm = {0.f, 0.f, 0.f, 0.f};
            f32x4 th = {0.f, 0.f, 0.f, 0.f};
            #pragma unroll
            for (int ks = 0; ks < 2; ++ks) {
                const bf16x8* p = Bv + (size_t)((c * 2 + ks) * 64 + ntg) * 192;
                const bf16x8 bh = p[0], bm = p[64], bl = p[128];
                ts = __builtin_amdgcn_mfma_f32_16x16x32_bf16(amd_[c][ks], bl, ts, 0, 0, 0);
                ts = __builtin_amdgcn_mfma_f32_16x16x32_bf16(alo[c][ks], bm, ts, 0, 0, 0);
                ts = __builtin_amdgcn_mfma_f32_16x16x32_bf16(ahi[c][ks], bl, ts, 0, 0, 0);
                ts = __builtin_amdgcn_mfma_f32_16x16x32_bf16(amd_[c][ks], bm, ts, 0, 0, 0);
                ts = __builtin_amdgcn_mfma_f32_16x16x32_bf16(alo[c][ks], bh, ts, 0, 0, 0);
                tm = __builtin_amdgcn_mfma_f32_16x16x32_bf16(ahi[c][ks], bm, tm, 0, 0, 0);
                tm = __builtin_amdgcn_mfma_f32_16x16x32_bf16(amd_[c][ks], bh, tm, 0, 0, 0);
                th = __builtin_amdgcn_mfma_f32_16x16x32_bf16(ahi[c][ks], bh, th, 0, 0, 0);
            }
            #pragma unroll
            for (int r = 0; r < 4; ++r)
                acc[c][nt][r] = (ts[r] + tm[r]) + th[r];
        }
    }
    __builtin_amdgcn_s_setprio(0);

    // ---- LN stats: per (w,g,c,r) partial over q (shfl) -> LDS -> 2-stage block reduce
    // (f32 two-stage tree kept: deterministic summation order)
    {
        float s_[2][4], q_[2][4];
        #pragma unroll
        for (int c = 0; c < 2; ++c)
            #pragma unroll
            for (int r = 0; r < 4; ++r) { s_[c][r] = 0.f; q_[c][r] = 0.f; }
        #pragma unroll
        for (int c = 0; c < 2; ++c)
            #pragma unroll
            for (int nt = 0; nt < 4; ++nt)
                #pragma unroll
                for (int r = 0; r < 4; ++r) {
                    const float v = acc[c][nt][r];
                    s_[c][r] += v;
                    q_[c][r] += v * v;
                }
        #pragma unroll
        for (int off = 1; off < 16; off <<= 1)
            #pragma unroll
            for (int c = 0; c < 2; ++c)
                #pragma unroll
                for (int r = 0; r < 4; ++r) {
                    s_[c][r] += __shfl_xor(s_[c][r], off);
                    q_[c][r] += __shfl_xor(q_[c][r], off);
                }
        if (q == 0) {
            #pragma unroll
            for (int c = 0; c < 2; ++c)
                #pragma unroll
                for (int r = 0; r < 4; ++r) {
                    stats[w][g][c][r][0] = s_[c][r];
                    stats[w][g][c][r][1] = q_[c][r];
                }
        }
    }
    __syncthreads();
    if (t < 64) {   // t = ((g*2+c)*4+r)*2+s
        const int gg = t >> 4, cc = (t >> 3) & 1, rr = (t >> 1) & 3, ss = t & 1;
        float S = 0.f;
        #pragma unroll
        for (int w2 = 0; w2 < 16; ++w2) S += stats[w2][gg][cc][rr][ss];
        statsF[t] = S;
    }
    __syncthreads();

    float mu_[2][4], rs_[2][4];
    #pragma unroll
    for (int c = 0; c < 2; ++c)
        #pragma unroll
        for (int r = 0; r < 4; ++r) {
            const float S = statsF[((g * 2 + c) * 4 + r) * 2 + 0];
            const float Q = statsF[((g * 2 + c) * 4 + r) * 2 + 1];
            const float mu = S * (1.f / 1024.f);
            float var = Q * (1.f / 1024.f) - mu * mu;
            var = fmaxf(var, 0.f);
            mu_[c][r] = mu;
            rs_[c][r] = rsqrtf(var + LN_EPS);
        }

    // ---- vp = silu(LN(y)) in-place
    const int dbase = w * 64 + q;
    #pragma unroll
    for (int nt = 0; nt < 4; ++nt) {
        const int d = dbase + 16 * nt;
        const float gam = gamma[d];
        const float bet = beta[d];
        #pragma unroll
        for (int c = 0; c < 2; ++c)
            #pragma unroll
            for (int r = 0; r < 4; ++r)
                acc[c][nt][r] = siluf((acc[c][nt][r] - mu_[c][r]) * rs_[c][r] * gam + bet);
    }

    // ---- sp cached once (reused by sign-count and epilogue)
    float spv[2][4];
    #pragma unroll
    for (int nt = 0; nt < 4; ++nt) {
        const int d = dbase + 16 * nt;
        spv[0][nt] = ws[SPOFF + d];
        spv[1][nt] = ws[SPOFF + 1024 + d];
    }

    // ---- S sign-counts: shfl over q, then ONE deterministic int atomicAdd stage
    // (integer adds commute exactly -> bit-identical S regardless of order; saves a barrier
    //  and the 16-iteration serial stage-2 loop)
    int cnt[2][4][2];
    #pragma unroll
    for (int c = 0; c < 2; ++c)
        #pragma unroll
        for (int r = 0; r < 4; ++r) { cnt[c][r][0] = 0; cnt[c][r][1] = 0; }
    #pragma unroll
    for (int nt = 0; nt < 4; ++nt) {
        #pragma unroll
        for (int c = 0; c < 2; ++c)
            #pragma unroll
            for (int r = 0; r < 4; ++r) {
                const float v = acc[c][nt][r];
                const unsigned int iv = __float_as_uint(v);
                cnt[c][r][0] += (int)((iv ^ __float_as_uint(v + spv[0][nt])) >> 31);
                cnt[c][r][1] += (int)((iv ^ __float_as_uint(v + spv[1][nt])) >> 31);
            }
    }
    #pragma unroll
    for (int off = 1; off < 16; off <<= 1)
        #pragma unroll
        for (int c = 0; c < 2; ++c)
            #pragma unroll
            for (int r = 0; r < 4; ++r) {
                cnt[c][r][0] += __shfl_xor(cnt[c][r][0], off);
                cnt[c][r][1] += __shfl_xor(cnt[c][r][1], off);
            }
    if (q == 0) {
        #pragma unroll
        for (int c = 0; c < 2; ++c)
            #pragma unroll
            for (int r = 0; r < 4; ++r) {
                atomicAdd(&sredF[((g * 2 + c) * 4 + r) * 2 + 0], cnt[c][r][0]);
                atomicAdd(&sredF[((g * 2 + c) * 4 + r) * 2 + 1], cnt[c][r][1]);
            }
    }
    __syncthreads();

    // ---- softmax over c
    float p0_[4][2], p1_[4][2];
    #pragma unroll
    for (int r = 0; r < 4; ++r)
        #pragma unroll
        for (int a = 0; a < 2; ++a) {
            const int t0 = sredF[((g * 2 + 0) * 4 + r) * 2 + a];
            const int t1 = sredF[((g * 2 + 1) * 4 + r) * 2 + a];
            const float S0 = 1.f - 2.f * (float)t0 * (1.f / 1024.f);
            const float S1 = 1.f - 2.f * (float)t1 * (1.f / 1024.f);
            const float m  = fmaxf(S0, S1);
            const float e0 = __expf(S0 - m), e1 = __expf(S1 - m);
            const float inv = __builtin_amdgcn_rcpf(e0 + e1);
            p0_[r][a] = e0 * inv;
            p1_[r][a] = e1 * inv;
        }

    // ---- attn + silu + store. otile is wave-private; DS ops in-order per wave.
    const int g2 = l >> 4, qq = l & 15;
    #pragma unroll
    for (int a = 0; a < 2; ++a) {
        #pragma unroll
        for (int r = 0; r < 4; ++r) {
            #pragma unroll
            for (int nt = 0; nt < 4; ++nt) {
                const float attn = p0_[r][a] * acc[0][nt][r] + p1_[r][a] * acc[1][nt][r];
                otile[w][g][16 * nt + q] = siluf(attn * spv[a][nt]);
            }
            __builtin_amdgcn_wave_barrier();
            const float4 v4 = *reinterpret_cast<const float4*>(&otile[w][g2][4 * qq]);
            *reinterpret_cast<float4*>(
                out + ((size_t)(b0 + 4 * g2 + r) * 2 + a) * 1024 + 64 * w + 4 * qq) = v4;
            __builtin_amdgcn_wave_barrier();
        }
    }
}

// ================= FALLBACK PATH (scalar, R2-proven) =================
// ws floats: [0,2176) hrev ; [2176,4224) sp
__global__ __launch_bounds__(256) void hd_prep_scalar(
    const float* __restrict__ h, const float* __restrict__ symbols,
    const float* __restrict__ gamma, const float* __restrict__ beta,
    float* __restrict__ ws)
{
    __shared__ float h_pad[2][1088];
    __shared__ float x_s[2][64];
    __shared__ float red[4][2];
    const int t = threadIdx.x;

    for (int idx = t; idx < 2 * 1088; idx += 256) {
        const int c = idx / 1088, j = idx - c * 1088;
        float v = 0.f;
        if (j >= 63 && j <= 1023) v = h[c * 961 + (j - 63)];
        h_pad[c][j] = v;
        const int src = 1086 - j;
        float vr = 0.f;
        if (src >= 63 && src <= 1023) vr = h[c * 961 + (src - 63)];
        ws[c * 1088 + j] = vr;
    }
    if (t < 128) x_s[t >> 6][t & 63] = symbols[t];
    __syncthreads();

    const int c = t >> 7, tt = t & 127;
    const int lane = t & 63, wid = t >> 6;
    const int jbase = 1023 - tt;

    float acc[8];
    #pragma unroll
    for (int k = 0; k < 8; ++k) acc[k] = 0.f;

    #pragma unroll 8
    for (int i = 0; i < 64; ++i) {
        const float xv = x_s[c][i];
        #pragma unroll
        for (int k = 0; k < 8; ++k)
            acc[k] = fmaf(xv, h_pad[c][jbase + i - 128 * k], acc[k]);
    }

    float ps = 0.f, pq = 0.f;
    #pragma unroll
    for (int k = 0; k < 8; ++k) { ps += acc[k]; pq += acc[k] * acc[k]; }
    #pragma unroll
    for (int off = 32; off; off >>= 1) {
        ps += __shfl_xor(ps, off);
        pq += __shfl_xor(pq, off);
    }
    if (lane == 0) { red[wid][0] = ps; red[wid][1] = pq; }
    __syncthreads();

    const float sum = red[2 * c][0] + red[2 * c + 1][0];
    const float sq  = red[2 * c][1] + red[2 * c + 1][1];
    const float mu  = sum * (1.f / 1024.f);
    float var = sq * (1.f / 1024.f) - mu * mu;
    var = fmaxf(var, 0.f);
    const float rs = rsqrtf(var + LN_EPS);

    #pragma unroll
    for (int k = 0; k < 8; ++k) {
        const int d = tt + 128 * k;
        const float ln = (acc[k] - mu) * rs * gamma[d] + beta[d];
        ws[2176 + c * 1024 + d] = siluf(ln);
    }
}

__global__ __launch_bounds__(256, 4) void hd_main_scalar(
    const float* __restrict__ values,
    const float* __restrict__ gamma, const float* __restrict__ beta,
    const float* __restrict__ ws, float* __restrict__ out)
{
    __shared__ float hrev[2][1088];
    __shared__ float red[4][16];
    __shared__ float redf[16];
    __shared__ float red2[4][16];
    __shared__ float redf2[16];

    const int t = threadIdx.x;
    const int lane = t & 63, wid = t >> 6;
    const size_t b0 = (size_t)blockIdx.x * 4;

    for (int idx = t; idx < 2 * 1088; idx += 256)
        (&hrev[0][0])[idx] = ws[idx];
    __syncthreads();

    float acc[4][2][4];
    #pragma unroll
    for (int b = 0; b < 4; ++b)
        #pragma unroll
        for (int c = 0; c < 2; ++c)
            #pragma unroll
            for (int k = 0; k < 4; ++k) acc[b][c][k] = 0.f;

    #pragma unroll 1
    for (int i0 = 0; i0 < 64; i0 += 8) {
        const int q0 = 56 + 4 * t - i0;
        float r[2][12];
        #pragma unroll
        for (int c = 0; c < 2; ++c) {
            const float4* p = reinterpret_cast<const float4*>(&hrev[c][q0]);
            const float4 a0 = p[0], a1 = p[1], a2 = p[2];
            r[c][0] = a0.x; r[c][1] = a0.y; r[c][2]  = a0.z; r[c][3]  = a0.w;
            r[c][4] = a1.x; r[c][5] = a1.y; r[c][6]  = a1.z; r[c][7]  = a1.w;
            r[c][8] = a2.x; r[c][9] = a2.y; r[c][10] = a2.z; r[c][11] = a2.w;
        }
        #pragma unroll
        for (int b = 0; b < 4; ++b) {
            #pragma unroll
            for (int c = 0; c < 2; ++c) {
                const float* xp = values + ((b0 + b) * 2 + c) * 64 + i0;
                #pragma unroll
                for (int il = 0; il < 8; ++il) {
                    const float xv = xp[il];
                    #pragma unroll
                    for (int k = 0; k < 4; ++k)
                        acc[b][c][k] = fmaf(xv, r[c][7 - il + k], acc[b][c][k]);
                }
            }
        }
    }

    {
        float v16[16];
        #pragma unroll
        for (int b = 0; b < 4; ++b)
            #pragma unroll
            for (int c = 0; c < 2; ++c) {
                const float a0 = acc[b][c][0], a1 = acc[b][c][1];
                const float a2 = acc[b][c][2], a3 = acc[b][c][3];
                v16[(b * 2 + c) * 2]     = a0 + a1 + a2 + a3;
                v16[(b * 2 + c) * 2 + 1] = a0 * a0 + a1 * a1 + a2 * a2 + a3 * a3;
            }
        #pragma unroll
        for (int off = 32; off; off >>= 1)
            #pragma unroll
            for (int v = 0; v < 16; ++v)
                v16[v] += __shfl_xor(v16[v], off);
        if (lane == 0) {
            #pragma unroll
            for (int v = 0; v < 16; ++v) red[wid][v] = v16[v];
        }
    }
    __syncthreads();
    if (t < 16) redf[t] = red[0][t] + red[1][t] + red[2][t] + red[3][t];
    __syncthreads();

    const float4 g4  = *reinterpret_cast<const float4*>(&gamma[4 * t]);
    const float4 be4 = *reinterpret_cast<const float4*>(&beta[4 * t]);
    float sp_r[2][4];
    #pragma unroll
    for (int a = 0; a < 2; ++a) {
        const float4 s4 = *reinterpret_cast<const float4*>(&ws[2176 + a * 1024 + 4 * t]);
        sp_r[a][0] = s4.x; sp_r[a][1] = s4.y; sp_r[a][2] = s4.z; sp_r[a][3] = s4.w;
    }
    const float gk[4] = {g4.x, g4.y, g4.z, g4.w};
    const float bk[4] = {be4.x, be4.y, be4.z, be4.w};

    #pragma unroll
    for (int b = 0; b < 4; ++b)
        #pragma unroll
        for (int c = 0; c < 2; ++c) {
            const float sum = redf[(b * 2 + c) * 2];
            const float sq  = redf[(b * 2 + c) * 2 + 1];
            const float mu  = sum * (1.f / 1024.f);
            float var = sq * (1.f / 1024.f) - mu * mu;
            var = fmaxf(var, 0.f);
            const float rs = rsqrtf(var + LN_EPS);
            #pragma unroll
            for (int k = 0; k < 4; ++k)
                acc[b][c][k] = siluf((acc[b][c][k] - mu) * rs * gk[k] + bk[k]);
        }

    {
        float v16[16];
        #pragma unroll
        for (int b = 0; b < 4; ++b)
            #pragma unroll
            for (int a = 0; a < 2; ++a)
                #pragma unroll
                for (int c = 0; c < 2; ++c) {
                    float s = 0.f;
                    #pragma unroll
                    for (int k = 0; k < 4; ++k)
                        s += sgnf(acc[b][c][k]) * sgnf(acc[b][c][k] + sp_r[a][k]);
                    v16[b * 4 + a * 2 + c] = s;
                }
        #pragma unroll
        for (int off = 32; off; off >>= 1)
            #pragma unroll
            for (int v = 0; v < 16; ++v)
                v16[v] += __shfl_xor(v16[v], off);
        if (lane == 0) {
            #pragma unroll
            for (int v = 0; v < 16; ++v) red2[wid][v] = v16[v];
        }
    }
    __syncthreads();
    if (t < 16) redf2[t] = red2[0][t] + red2[1][t] + red2[2][t] + red2[3][t];
    __syncthreads();

    #pragma unroll
    for (int b = 0; b < 4; ++b) {
        #pragma unroll
        for (int a = 0; a < 2; ++a) {
            const float s0 = redf2[b * 4 + a * 2 + 0] * (1.f / 1024.f);
            const float s1 = redf2[b * 4 + a * 2 + 1] * (1.f / 1024.f);
            const float m  = fmaxf(s0, s1);
            const float e0 = __expf(s0 - m), e1 = __expf(s1 - m);
            const float inv = 1.f / (e0 + e1);
            const float p0 = e0 * inv, p1 = e1 * inv;
            float4 o;
            o.x = siluf((p0 * acc[b][0][0] + p1 * acc[b][1][0]) * sp_r[a][0]);
            o.y = siluf((p0 * acc[b][0][1] + p1 * acc[b][1][1]) * sp_r[a][1]);
            o.z = siluf((p0 * acc[b][0][2] + p1 * acc[b][1][2]) * sp_r[a][2]);
            o.w = siluf((p0 * acc[b][0][3] + p1 * acc[b][1][3]) * sp_r[a][3]);
            *reinterpret_cast<float4*>(out + ((b0 + b) * 2 + a) * 1024 + 4 * t) = o;
        }
    }
}

extern "C" void kernel_launch(void* const* d_in, const int* in_sizes, int n_in,
                              void* d_out, int out_size, void* d_ws, size_t ws_size,
                              hipStream_t stream) {
    const float* values  = (const float*)d_in[0];
    const float* h       = (const float*)d_in[1];
    const float* gamma   = (const float*)d_in[2];
    const float* beta    = (const float*)d_in[3];
    const float* symbols = (const float*)d_in[4];
    float* out = (float*)d_out;
    float* ws  = (float*)d_ws;

    const int B = in_sizes[0] / 128;   // 16384

    if (ws_size >= 794624) {
        // fast MFMA path
        hipLaunchKernelGGL(hd_prep_sp, dim3(1), dim3(256), 0, stream,
                           h, symbols, gamma, beta, ws);
        hipLaunchKernelGGL(hd_prep_bpack, dim3(256), dim3(256), 0, stream, h, ws);
        hipLaunchKernelGGL(hd_main_mfma, dim3(B / 16), dim3(1024), 0, stream,
                           values, gamma, beta, ws, out);
    } else {
        // scalar fallback (R2-proven)
        hipLaunchKernelGGL(hd_prep_scalar, dim3(1), dim3(256), 0, stream,
                           h, symbols, gamma, beta, ws);
        hipLaunchKernelGGL(hd_main_scalar, dim3(B / 4), dim3(256), 0, stream,
                           values, gamma, beta, ws, out);
    }
}

// Round 17
// 107.381 us; speedup vs baseline: 1.0890x; 1.0004x over previous
//
#include <hip/hip_runtime.h>

#define LN_EPS 1e-3f

typedef __attribute__((ext_vector_type(8))) short bf16x8;
typedef __attribute__((ext_vector_type(4))) float f32x4;

static __device__ __forceinline__ float sgnf(float x) {
    return (x > 0.f) ? 1.f : ((x < 0.f) ? -1.f : 0.f);
}
// silu via single-instruction v_rcp_f32: denominator > 0 so sign(silu(x)) == sign(x).
static __device__ __forceinline__ float siluf(float x) {
    return x * __builtin_amdgcn_rcpf(1.f + __expf(-x));
}

// round-to-nearest-even fp32 -> bf16 bits
static __device__ __forceinline__ unsigned short f2bf(float f) {
    unsigned int u = __float_as_uint(f);
    return (unsigned short)((u + 0x7fffu + ((u >> 16) & 1u)) >> 16);
}
static __device__ __forceinline__ float bf2f(unsigned short s) {
    return __uint_as_float(((unsigned int)s) << 16);
}
// exact 3-way bf16 split: v = hi + mid + lo (+ O(2^-27) rel)
static __device__ __forceinline__ void split3(float v, unsigned short& hi,
                                              unsigned short& mid, unsigned short& lo) {
    hi = f2bf(v);
    const float r1 = v - bf2f(hi);       // exact (Sterbenz)
    mid = f2bf(r1);
    const float r2 = r1 - bf2f(mid);     // exact
    lo = f2bf(r2);
}

// ================= FAST PATH (MFMA) — requires ws_size >= 794624 =================
// ws layout (bytes):
//   [0, 786432)          Bpack: bf16 H^T fragments, 3-way split, part-major (coalesced)
//     bf16x8 index = ((c*2+ks)*64 + ntg)*192 + part*64 + lane
//   [786432, 794624)     sp[2][1024] fp32   (float offset 196608)
#define SPOFF 196608

// ---------------- fast prep 1: sp ----------------
__global__ __launch_bounds__(256) void hd_prep_sp(
    const float* __restrict__ h, const float* __restrict__ symbols,
    const float* __restrict__ gamma, const float* __restrict__ beta,
    float* __restrict__ ws)
{
    __shared__ float h_pad[2][1088];
    __shared__ float x_s[2][64];
    __shared__ float red[4][2];
    const int t = threadIdx.x;

    for (int idx = t; idx < 2 * 1088; idx += 256) {
        const int c = idx / 1088, j = idx - c * 1088;
        float v = 0.f;
        if (j >= 63 && j <= 1023) v = h[c * 961 + (j - 63)];
        h_pad[c][j] = v;
    }
    if (t < 128) x_s[t >> 6][t & 63] = symbols[t];
    __syncthreads();

    const int c = t >> 7, tt = t & 127;
    const int lane = t & 63, wid = t >> 6;
    const int jbase = 1023 - tt;

    float acc[8];
    #pragma unroll
    for (int k = 0; k < 8; ++k) acc[k] = 0.f;

    #pragma unroll 8
    for (int i = 0; i < 64; ++i) {
        const float xv = x_s[c][i];
        #pragma unroll
        for (int k = 0; k < 8; ++k)
            acc[k] = fmaf(xv, h_pad[c][jbase + i - 128 * k], acc[k]);
    }

    float ps = 0.f, pq = 0.f;
    #pragma unroll
    for (int k = 0; k < 8; ++k) { ps += acc[k]; pq += acc[k] * acc[k]; }
    #pragma unroll
    for (int off = 32; off; off >>= 1) {
        ps += __shfl_xor(ps, off);
        pq += __shfl_xor(pq, off);
    }
    if (lane == 0) { red[wid][0] = ps; red[wid][1] = pq; }
    __syncthreads();

    const float sum = red[2 * c][0] + red[2 * c + 1][0];
    const float sq  = red[2 * c][1] + red[2 * c + 1][1];
    const float mu  = sum * (1.f / 1024.f);
    float var = sq * (1.f / 1024.f) - mu * mu;
    var = fmaxf(var, 0.f);
    const float rs = rsqrtf(var + LN_EPS);

    #pragma unroll
    for (int k = 0; k < 8; ++k) {
        const int d = tt + 128 * k;
        const float ln = (acc[k] - mu) * rs * gamma[d] + beta[d];
        ws[SPOFF + c * 1024 + d] = siluf(ln);
    }
}

// ---------------- fast prep 2: Bpack (part-major layout) ----------------
__global__ __launch_bounds__(256) void hd_prep_bpack(
    const float* __restrict__ h, float* __restrict__ ws)
{
    unsigned short* Bp = (unsigned short*)ws;
    const int total = 2 * 2 * 64 * 64 * 8;   // 131072 positions, 3 parts each
    for (int e = blockIdx.x * 256 + threadIdx.x; e < total; e += gridDim.x * 256) {
        const int j   = e & 7;
        const int l   = (e >> 3) & 63;
        const int ntg = (e >> 9) & 63;
        const int ks  = (e >> 15) & 1;
        const int c   = (e >> 16) & 1;
        const int H = 1023 - (16 * ntg + (l & 15)) + 32 * ks + 8 * (l >> 4) + j;
        float v = 0.f;
        if (H >= 63 && H <= 1023) v = h[c * 961 + (H - 63)];
        unsigned short hi, mid, lo;
        split3(v, hi, mid, lo);
        const int T = (c * 2 + ks) * 64 + ntg;
        Bp[((T * 192 +   0 + l)) * 8 + j] = hi;
        Bp[((T * 192 +  64 + l)) * 8 + j] = mid;
        Bp[((T * 192 + 128 + l)) * 8 + j] = lo;
    }
}

// ---------------- fast main: 1024 thr (16 waves), wave w -> d in [64w, 64w+64) ----------------
// LDS padded past 80KB on purpose: forces 1 block/CU (16 waves, 4/SIMD) so the register
// allocator budgets 128 VGPRs instead of 64 -> A-frags stay resident, B loads pipeline deep.
__global__ __launch_bounds__(1024, 4) void hd_main_mfma(
    const float* __restrict__ values,
    const float* __restrict__ gamma, const float* __restrict__ beta,
    const float* __restrict__ ws, float* __restrict__ out)
{
    __shared__ __align__(16) unsigned short a_lds[2][2][3][16][40];
    __shared__ float stats[16][4][2][4][2];  // [wave][g][c][r][sum,sq]
    __shared__ float statsF[64];             // [g][c][r][s]
    __shared__ int   sredF [64];             // [g][c][r][a] — atomic accumulator
    __shared__ float otile[16][4][72];       // per-WAVE store tile
    __shared__ float lds_pad[11520];         // occupancy control: total LDS > 80KB -> 1 block/CU

    const int t = threadIdx.x;
    const int w = t >> 6, l = t & 63;
    const int g = l >> 4, q = l & 15;
    const int b0 = blockIdx.x * 16;

    // opaque write keeps lds_pad allocated (never true at runtime; unprovable at compile time)
    if (values == nullptr) lds_pad[t] = 1.f;

    // zero the sign-count accumulator before the first barrier
    if (t < 64) sredF[t] = 0;

    // ---- cooperative A-fragment prep: 2048 x-values, thread t split3's values 2t, 2t+1
    {
        const float2 xv2 = *reinterpret_cast<const float2*>(
            values + (size_t)b0 * 128 + 2 * t);
        #pragma unroll
        for (int u = 0; u < 2; ++u) {
            const int v  = 2 * t + u;
            const int q_ = v >> 7, c_ = (v >> 6) & 1, k_ = v & 63;
            const int ks_ = k_ >> 5, gj = k_ & 31;
            unsigned short hb, mb, lb;
            split3(u == 0 ? xv2.x : xv2.y, hb, mb, lb);
            a_lds[c_][ks_][0][q_][gj] = hb;
            a_lds[c_][ks_][1][q_][gj] = mb;
            a_lds[c_][ks_][2][q_][gj] = lb;
        }
    }
    __syncthreads();

    // ---- A fragments from LDS (bit-identical to per-thread split)
    bf16x8 ahi[2][2], amd_[2][2], alo[2][2];
    #pragma unroll
    for (int c = 0; c < 2; ++c)
        #pragma unroll
        for (int ks = 0; ks < 2; ++ks) {
            ahi[c][ks]  = *reinterpret_cast<const bf16x8*>(&a_lds[c][ks][0][q][8 * g]);
            amd_[c][ks] = *reinterpret_cast<const bf16x8*>(&a_lds[c][ks][1][q][8 * g]);
            alo[c][ks]  = *reinterpret_cast<const bf16x8*>(&a_lds[c][ks][2][q][8 * g]);
        }

    // ---- MFMA (R10 body)
    const bf16x8* Bv = reinterpret_cast<const bf16x8*>(ws) + l;
    f32x4 acc[2][4];
    #pragma unroll
    for (int c = 0; c < 2; ++c)
        #pragma unroll
        for (int nt = 0; nt < 4; ++nt)
            acc[c][nt] = (f32x4){0.f, 0.f, 0.f, 0.f};

    __builtin_amdgcn_s_setprio(1);
    #pragma unroll
    for (int nt = 0; nt < 4; ++nt) {
        const int ntg = w * 4 + nt;
        #pragma unroll
        for (int c = 0; c < 2; ++c) {
            f32x4 ts = {0.f, 0.f, 0.f, 0.f};
            f32x4 tm = {0.f, 0.f, 0.f, 0.f};
            f32x4 th = {0.f, 0.f, 0.f, 0.f};
            #pragma unroll
            for (int ks = 0; ks < 2; ++ks) {
                const bf16x8* p = Bv + (size_t)((c * 2 + ks) * 64 + ntg) * 192;
                const bf16x8 bh = p[0], bm = p[64], bl = p[128];
                ts = __builtin_amdgcn_mfma_f32_16x16x32_bf16(amd_[c][ks], bl, ts, 0, 0, 0);
                ts = __builtin_amdgcn_mfma_f32_16x16x32_bf16(alo[c][ks], bm, ts, 0, 0, 0);
                ts = __builtin_amdgcn_mfma_f32_16x16x32_bf16(ahi[c][ks], bl, ts, 0, 0, 0);
                ts = __builtin_amdgcn_mfma_f32_16x16x32_bf16(amd_[c][ks], bm, ts, 0, 0, 0);
                ts = __builtin_amdgcn_mfma_f32_16x16x32_bf16(alo[c][ks], bh, ts, 0, 0, 0);
                tm = __builtin_amdgcn_mfma_f32_16x16x32_bf16(ahi[c][ks], bm, tm, 0, 0, 0);
                tm = __builtin_amdgcn_mfma_f32_16x16x32_bf16(amd_[c][ks], bh, tm, 0, 0, 0);
                th = __builtin_amdgcn_mfma_f32_16x16x32_bf16(ahi[c][ks], bh, th, 0, 0, 0);
            }
            #pragma unroll
            for (int r = 0; r < 4; ++r)
                acc[c][nt][r] = (ts[r] + tm[r]) + th[r];
        }
    }
    __builtin_amdgcn_s_setprio(0);

    // ---- LN stats: per (w,g,c,r) partial over q (shfl) -> LDS -> 2-stage block reduce
    {
        float s_[2][4], q_[2][4];
        #pragma unroll
        for (int c = 0; c < 2; ++c)
            #pragma unroll
            for (int r = 0; r < 4; ++r) { s_[c][r] = 0.f; q_[c][r] = 0.f; }
        #pragma unroll
        for (int c = 0; c < 2; ++c)
            #pragma unroll
            for (int nt = 0; nt < 4; ++nt)
                #pragma unroll
                for (int r = 0; r < 4; ++r) {
                    const float v = acc[c][nt][r];
                    s_[c][r] += v;
                    q_[c][r] += v * v;
                }
        #pragma unroll
        for (int off = 1; off < 16; off <<= 1)
            #pragma unroll
            for (int c = 0; c < 2; ++c)
                #pragma unroll
                for (int r = 0; r < 4; ++r) {
                    s_[c][r] += __shfl_xor(s_[c][r], off);
                    q_[c][r] += __shfl_xor(q_[c][r], off);
                }
        if (q == 0) {
            #pragma unroll
            for (int c = 0; c < 2; ++c)
                #pragma unroll
                for (int r = 0; r < 4; ++r) {
                    stats[w][g][c][r][0] = s_[c][r];
                    stats[w][g][c][r][1] = q_[c][r];
                }
        }
    }
    __syncthreads();
    if (t < 64) {   // t = ((g*2+c)*4+r)*2+s
        const int gg = t >> 4, cc = (t >> 3) & 1, rr = (t >> 1) & 3, ss = t & 1;
        float S = 0.f;
        #pragma unroll
        for (int w2 = 0; w2 < 16; ++w2) S += stats[w2][gg][cc][rr][ss];
        statsF[t] = S;
    }
    __syncthreads();

    float mu_[2][4], rs_[2][4];
    #pragma unroll
    for (int c = 0; c < 2; ++c)
        #pragma unroll
        for (int r = 0; r < 4; ++r) {
            const float S = statsF[((g * 2 + c) * 4 + r) * 2 + 0];
            const float Q = statsF[((g * 2 + c) * 4 + r) * 2 + 1];
            const float mu = S * (1.f / 1024.f);
            float var = Q * (1.f / 1024.f) - mu * mu;
            var = fmaxf(var, 0.f);
            mu_[c][r] = mu;
            rs_[c][r] = rsqrtf(var + LN_EPS);
        }

    // ---- vp = silu(LN(y)) in-place
    const int dbase = w * 64 + q;
    #pragma unroll
    for (int nt = 0; nt < 4; ++nt) {
        const int d = dbase + 16 * nt;
        const float gam = gamma[d];
        const float bet = beta[d];
        #pragma unroll
        for (int c = 0; c < 2; ++c)
            #pragma unroll
            for (int r = 0; r < 4; ++r)
                acc[c][nt][r] = siluf((acc[c][nt][r] - mu_[c][r]) * rs_[c][r] * gam + bet);
    }

    // ---- sp cached once (reused by sign-count and epilogue)
    float spv[2][4];
    #pragma unroll
    for (int nt = 0; nt < 4; ++nt) {
        const int d = dbase + 16 * nt;
        spv[0][nt] = ws[SPOFF + d];
        spv[1][nt] = ws[SPOFF + 1024 + d];
    }

    // ---- S sign-counts: shfl over q, then ONE deterministic int atomicAdd stage
    int cnt[2][4][2];
    #pragma unroll
    for (int c = 0; c < 2; ++c)
        #pragma unroll
        for (int r = 0; r < 4; ++r) { cnt[c][r][0] = 0; cnt[c][r][1] = 0; }
    #pragma unroll
    for (int nt = 0; nt < 4; ++nt) {
        #pragma unroll
        for (int c = 0; c < 2; ++c)
            #pragma unroll
            for (int r = 0; r < 4; ++r) {
                const float v = acc[c][nt][r];
                const unsigned int iv = __float_as_uint(v);
                cnt[c][r][0] += (int)((iv ^ __float_as_uint(v + spv[0][nt])) >> 31);
                cnt[c][r][1] += (int)((iv ^ __float_as_uint(v + spv[1][nt])) >> 31);
            }
    }
    #pragma unroll
    for (int off = 1; off < 16; off <<= 1)
        #pragma unroll
        for (int c = 0; c < 2; ++c)
            #pragma unroll
            for (int r = 0; r < 4; ++r) {
                cnt[c][r][0] += __shfl_xor(cnt[c][r][0], off);
                cnt[c][r][1] += __shfl_xor(cnt[c][r][1], off);
            }
    if (q == 0) {
        #pragma unroll
        for (int c = 0; c < 2; ++c)
            #pragma unroll
            for (int r = 0; r < 4; ++r) {
                atomicAdd(&sredF[((g * 2 + c) * 4 + r) * 2 + 0], cnt[c][r][0]);
                atomicAdd(&sredF[((g * 2 + c) * 4 + r) * 2 + 1], cnt[c][r][1]);
            }
    }
    __syncthreads();

    // ---- softmax over c
    float p0_[4][2], p1_[4][2];
    #pragma unroll
    for (int r = 0; r < 4; ++r)
        #pragma unroll
        for (int a = 0; a < 2; ++a) {
            const int t0 = sredF[((g * 2 + 0) * 4 + r) * 2 + a];
            const int t1 = sredF[((g * 2 + 1) * 4 + r) * 2 + a];
            const float S0 = 1.f - 2.f * (float)t0 * (1.f / 1024.f);
            const float S1 = 1.f - 2.f * (float)t1 * (1.f / 1024.f);
            const float m  = fmaxf(S0, S1);
            const float e0 = __expf(S0 - m), e1 = __expf(S1 - m);
            const float inv = __builtin_amdgcn_rcpf(e0 + e1);
            p0_[r][a] = e0 * inv;
            p1_[r][a] = e1 * inv;
        }

    // ---- attn + silu + store. otile is wave-private; DS ops in-order per wave.
    const int g2 = l >> 4, qq = l & 15;
    #pragma unroll
    for (int a = 0; a < 2; ++a) {
        #pragma unroll
        for (int r = 0; r < 4; ++r) {
            #pragma unroll
            for (int nt = 0; nt < 4; ++nt) {
                const float attn = p0_[r][a] * acc[0][nt][r] + p1_[r][a] * acc[1][nt][r];
                otile[w][g][16 * nt + q] = siluf(attn * spv[a][nt]);
            }
            __builtin_amdgcn_wave_barrier();
            const float4 v4 = *reinterpret_cast<const float4*>(&otile[w][g2][4 * qq]);
            *reinterpret_cast<float4*>(
                out + ((size_t)(b0 + 4 * g2 + r) * 2 + a) * 1024 + 64 * w + 4 * qq) = v4;
            __builtin_amdgcn_wave_barrier();
        }
    }
}

// ================= FALLBACK PATH (scalar, R2-proven) =================
// ws floats: [0,2176) hrev ; [2176,4224) sp
__global__ __launch_bounds__(256) void hd_prep_scalar(
    const float* __restrict__ h, const float* __restrict__ symbols,
    const float* __restrict__ gamma, const float* __restrict__ beta,
    float* __restrict__ ws)
{
    __shared__ float h_pad[2][1088];
    __shared__ float x_s[2][64];
    __shared__ float red[4][2];
    const int t = threadIdx.x;

    for (int idx = t; idx < 2 * 1088; idx += 256) {
        const int c = idx / 1088, j = idx - c * 1088;
        float v = 0.f;
        if (j >= 63 && j <= 1023) v = h[c * 961 + (j - 63)];
        h_pad[c][j] = v;
        const int src = 1086 - j;
        float vr = 0.f;
        if (src >= 63 && src <= 1023) vr = h[c * 961 + (src - 63)];
        ws[c * 1088 + j] = vr;
    }
    if (t < 128) x_s[t >> 6][t & 63] = symbols[t];
    __syncthreads();

    const int c = t >> 7, tt = t & 127;
    const int lane = t & 63, wid = t >> 6;
    const int jbase = 1023 - tt;

    float acc[8];
    #pragma unroll
    for (int k = 0; k < 8; ++k) acc[k] = 0.f;

    #pragma unroll 8
    for (int i = 0; i < 64; ++i) {
        const float xv = x_s[c][i];
        #pragma unroll
        for (int k = 0; k < 8; ++k)
            acc[k] = fmaf(xv, h_pad[c][jbase + i - 128 * k], acc[k]);
    }

    float ps = 0.f, pq = 0.f;
    #pragma unroll
    for (int k = 0; k < 8; ++k) { ps += acc[k]; pq += acc[k] * acc[k]; }
    #pragma unroll
    for (int off = 32; off; off >>= 1) {
        ps += __shfl_xor(ps, off);
        pq += __shfl_xor(pq, off);
    }
    if (lane == 0) { red[wid][0] = ps; red[wid][1] = pq; }
    __syncthreads();

    const float sum = red[2 * c][0] + red[2 * c + 1][0];
    const float sq  = red[2 * c][1] + red[2 * c + 1][1];
    const float mu  = sum * (1.f / 1024.f);
    float var = sq * (1.f / 1024.f) - mu * mu;
    var = fmaxf(var, 0.f);
    const float rs = rsqrtf(var + LN_EPS);

    #pragma unroll
    for (int k = 0; k < 8; ++k) {
        const int d = tt + 128 * k;
        const float ln = (acc[k] - mu) * rs * gamma[d] + beta[d];
        ws[2176 + c * 1024 + d] = siluf(ln);
    }
}

__global__ __launch_bounds__(256, 4) void hd_main_scalar(
    const float* __restrict__ values,
    const float* __restrict__ gamma, const float* __restrict__ beta,
    const float* __restrict__ ws, float* __restrict__ out)
{
    __shared__ float hrev[2][1088];
    __shared__ float red[4][16];
    __shared__ float redf[16];
    __shared__ float red2[4][16];
    __shared__ float redf2[16];

    const int t = threadIdx.x;
    const int lane = t & 63, wid = t >> 6;
    const size_t b0 = (size_t)blockIdx.x * 4;

    for (int idx = t; idx < 2 * 1088; idx += 256)
        (&hrev[0][0])[idx] = ws[idx];
    __syncthreads();

    float acc[4][2][4];
    #pragma unroll
    for (int b = 0; b < 4; ++b)
        #pragma unroll
        for (int c = 0; c < 2; ++c)
            #pragma unroll
            for (int k = 0; k < 4; ++k) acc[b][c][k] = 0.f;

    #pragma unroll 1
    for (int i0 = 0; i0 < 64; i0 += 8) {
        const int q0 = 56 + 4 * t - i0;
        float r[2][12];
        #pragma unroll
        for (int c = 0; c < 2; ++c) {
            const float4* p = reinterpret_cast<const float4*>(&hrev[c][q0]);
            const float4 a0 = p[0], a1 = p[1], a2 = p[2];
            r[c][0] = a0.x; r[c][1] = a0.y; r[c][2]  = a0.z; r[c][3]  = a0.w;
            r[c][4] = a1.x; r[c][5] = a1.y; r[c][6]  = a1.z; r[c][7]  = a1.w;
            r[c][8] = a2.x; r[c][9] = a2.y; r[c][10] = a2.z; r[c][11] = a2.w;
        }
        #pragma unroll
        for (int b = 0; b < 4; ++b) {
            #pragma unroll
            for (int c = 0; c < 2; ++c) {
                const float* xp = values + ((b0 + b) * 2 + c) * 64 + i0;
                #pragma unroll
                for (int il = 0; il < 8; ++il) {
                    const float xv = xp[il];
                    #pragma unroll
                    for (int k = 0; k < 4; ++k)
                        acc[b][c][k] = fmaf(xv, r[c][7 - il + k], acc[b][c][k]);
                }
            }
        }
    }

    {
        float v16[16];
        #pragma unroll
        for (int b = 0; b < 4; ++b)
            #pragma unroll
            for (int c = 0; c < 2; ++c) {
                const float a0 = acc[b][c][0], a1 = acc[b][c][1];
                const float a2 = acc[b][c][2], a3 = acc[b][c][3];
                v16[(b * 2 + c) * 2]     = a0 + a1 + a2 + a3;
                v16[(b * 2 + c) * 2 + 1] = a0 * a0 + a1 * a1 + a2 * a2 + a3 * a3;
            }
        #pragma unroll
        for (int off = 32; off; off >>= 1)
            #pragma unroll
            for (int v = 0; v < 16; ++v)
                v16[v] += __shfl_xor(v16[v], off);
        if (lane == 0) {
            #pragma unroll
            for (int v = 0; v < 16; ++v) red[wid][v] = v16[v];
        }
    }
    __syncthreads();
    if (t < 16) redf[t] = red[0][t] + red[1][t] + red[2][t] + red[3][t];
    __syncthreads();

    const float4 g4  = *reinterpret_cast<const float4*>(&gamma[4 * t]);
    const float4 be4 = *reinterpret_cast<const float4*>(&beta[4 * t]);
    float sp_r[2][4];
    #pragma unroll
    for (int a = 0; a < 2; ++a) {
        const float4 s4 = *reinterpret_cast<const float4*>(&ws[2176 + a * 1024 + 4 * t]);
        sp_r[a][0] = s4.x; sp_r[a][1] = s4.y; sp_r[a][2] = s4.z; sp_r[a][3] = s4.w;
    }
    const float gk[4] = {g4.x, g4.y, g4.z, g4.w};
    const float bk[4] = {be4.x, be4.y, be4.z, be4.w};

    #pragma unroll
    for (int b = 0; b < 4; ++b)
        #pragma unroll
        for (int c = 0; c < 2; ++c) {
            const float sum = redf[(b * 2 + c) * 2];
            const float sq  = redf[(b * 2 + c) * 2 + 1];
            const float mu  = sum * (1.f / 1024.f);
            float var = sq * (1.f / 1024.f) - mu * mu;
            var = fmaxf(var, 0.f);
            const float rs = rsqrtf(var + LN_EPS);
            #pragma unroll
            for (int k = 0; k < 4; ++k)
                acc[b][c][k] = siluf((acc[b][c][k] - mu) * rs * gk[k] + bk[k]);
        }

    {
        float v16[16];
        #pragma unroll
        for (int b = 0; b < 4; ++b)
            #pragma unroll
            for (int a = 0; a < 2; ++a)
                #pragma unroll
                for (int c = 0; c < 2; ++c) {
                    float s = 0.f;
                    #pragma unroll
                    for (int k = 0; k < 4; ++k)
                        s += sgnf(acc[b][c][k]) * sgnf(acc[b][c][k] + sp_r[a][k]);
                    v16[b * 4 + a * 2 + c] = s;
                }
        #pragma unroll
        for (int off = 32; off; off >>= 1)
            #pragma unroll
            for (int v = 0; v < 16; ++v)
                v16[v] += __shfl_xor(v16[v], off);
        if (lane == 0) {
            #pragma unroll
            for (int v = 0; v < 16; ++v) red2[wid][v] = v16[v];
        }
    }
    __syncthreads();
    if (t < 16) redf2[t] = red2[0][t] + red2[1][t] + red2[2][t] + red2[3][t];
    __syncthreads();

    #pragma unroll
    for (int b = 0; b < 4; ++b) {
        #pragma unroll
        for (int a = 0; a < 2; ++a) {
            const float s0 = redf2[b * 4 + a * 2 + 0] * (1.f / 1024.f);
            const float s1 = redf2[b * 4 + a * 2 + 1] * (1.f / 1024.f);
            const float m  = fmaxf(s0, s1);
            const float e0 = __expf(s0 - m), e1 = __expf(s1 - m);
            const float inv = 1.f / (e0 + e1);
            const float p0 = e0 * inv, p1 = e1 * inv;
            float4 o;
            o.x = siluf((p0 * acc[b][0][0] + p1 * acc[b][1][0]) * sp_r[a][0]);
            o.y = siluf((p0 * acc[b][0][1] + p1 * acc[b][1][1]) * sp_r[a][1]);
            o.z = siluf((p0 * acc[b][0][2] + p1 * acc[b][1][2]) * sp_r[a][2]);
            o.w = siluf((p0 * acc[b][0][3] + p1 * acc[b][1][3]) * sp_r[a][3]);
            *reinterpret_cast<float4*>(out + ((b0 + b) * 2 + a) * 1024 + 4 * t) = o;
        }
    }
}

extern "C" void kernel_launch(void* const* d_in, const int* in_sizes, int n_in,
                              void* d_out, int out_size, void* d_ws, size_t ws_size,
                              hipStream_t stream) {
    const float* values  = (const float*)d_in[0];
    const float* h       = (const float*)d_in[1];
    const float* gamma   = (const float*)d_in[2];
    const float* beta    = (const float*)d_in[3];
    const float* symbols = (const float*)d_in[4];
    float* out = (float*)d_out;
    float* ws  = (float*)d_ws;

    const int B = in_sizes[0] / 128;   // 16384

    if (ws_size >= 794624) {
        // fast MFMA path
        hipLaunchKernelGGL(hd_prep_sp, dim3(1), dim3(256), 0, stream,
                           h, symbols, gamma, beta, ws);
        hipLaunchKernelGGL(hd_prep_bpack, dim3(256), dim3(256), 0, stream, h, ws);
        hipLaunchKernelGGL(hd_main_mfma, dim3(B / 16), dim3(1024), 0, stream,
                           values, gamma, beta, ws, out);
    } else {
        // scalar fallback (R2-proven)
        hipLaunchKernelGGL(hd_prep_scalar, dim3(1), dim3(256), 0, stream,
                           h, symbols, gamma, beta, ws);
        hipLaunchKernelGGL(hd_main_scalar, dim3(B / 4), dim3(256), 0, stream,
                           values, gamma, beta, ws, out);
    }
}